// Round 14
// baseline (6073.865 us; speedup 1.0000x reference)
//
#include <hip/hip_runtime.h>
#include <hip/hip_cooperative_groups.h>
#include <math.h>

namespace cg = cooperative_groups;

#define BB   128      // batch
#define T    45
#define E    300
#define HH   1024
#define G4   4096
#define HW   196      // 14*14
#define NPX  (BB*HW)  // 25088
#define C0   1026
#define CM   128
#define CR   130
#define TCH  15       // X-chunk timesteps (45 = 3*15)

static __device__ __forceinline__ float sigm(float x) { return 1.f / (1.f + __expf(-x)); }

// ---------------- embedding gather: emb[t][b][e] = lookup[que[b][t]][e] ----------------
__global__ void k_embed(const int* __restrict__ que, const float* __restrict__ lookup,
                        float* __restrict__ emb) {
    int idx = blockIdx.x * 256 + threadIdx.x;
    if (idx >= T * BB * E) return;
    int e = idx % E;
    int n = idx / E;
    int b = n % BB;
    int t = n / BB;
    int q = que[b * T + t];
    emb[idx] = lookup[(size_t)q * E + e];
}

// ---------------- generic NT GEMM: C[m][n] = sum A[m][k]*Bw[n][k] (+add)(+bias)(relu) ----
template <int BM, int BN, int TM, int TN>
__global__ __launch_bounds__(256) void k_gemm_nt(
    const float* __restrict__ A, int lda,
    const float* __restrict__ Bw, int ldb,
    const float* __restrict__ add,
    const float* __restrict__ bias,
    float* __restrict__ C, int ldc,
    int M, int N, int K, int relu) {
    constexpr int KT = 16;
    constexpr int TX = BN / TN;
    __shared__ alignas(16) float As[KT][BM + 4];
    __shared__ alignas(16) float Bs[KT][BN + 4];
    const int tid = threadIdx.x;
    const int tx = tid % TX, ty = tid / TX;
    const int r0 = blockIdx.x * BM, c0 = blockIdx.y * BN;
    float acc[TM][TN] = {};
    for (int k0 = 0; k0 < K; k0 += KT) {
#pragma unroll
        for (int l = tid; l < BM * KT; l += 256) {
            int m = l / KT, k = l % KT;
            int gm = r0 + m, gk = k0 + k;
            As[k][m] = (gm < M && gk < K) ? A[(size_t)gm * lda + gk] : 0.f;
        }
#pragma unroll
        for (int l = tid; l < BN * KT; l += 256) {
            int n = l / KT, k = l % KT;
            int gn = c0 + n, gk = k0 + k;
            Bs[k][n] = (gn < N && gk < K) ? Bw[(size_t)gn * ldb + gk] : 0.f;
        }
        __syncthreads();
#pragma unroll
        for (int k = 0; k < KT; ++k) {
            float ar[TM], br[TN];
            if constexpr ((TM & 3) == 0) {
#pragma unroll
                for (int i = 0; i < TM; i += 4) {
                    float4 v = *(const float4*)&As[k][ty * TM + i];
                    ar[i] = v.x; ar[i + 1] = v.y; ar[i + 2] = v.z; ar[i + 3] = v.w;
                }
            } else if constexpr ((TM & 1) == 0) {
#pragma unroll
                for (int i = 0; i < TM; i += 2) {
                    float2 v = *(const float2*)&As[k][ty * TM + i];
                    ar[i] = v.x; ar[i + 1] = v.y;
                }
            } else {
#pragma unroll
                for (int i = 0; i < TM; ++i) ar[i] = As[k][ty * TM + i];
            }
            if constexpr ((TN & 3) == 0) {
#pragma unroll
                for (int j = 0; j < TN; j += 4) {
                    float4 v = *(const float4*)&Bs[k][tx * TN + j];
                    br[j] = v.x; br[j + 1] = v.y; br[j + 2] = v.z; br[j + 3] = v.w;
                }
            } else if constexpr ((TN & 1) == 0) {
#pragma unroll
                for (int j = 0; j < TN; j += 2) {
                    float2 v = *(const float2*)&Bs[k][tx * TN + j];
                    br[j] = v.x; br[j + 1] = v.y;
                }
            } else {
#pragma unroll
                for (int j = 0; j < TN; ++j) br[j] = Bs[k][tx * TN + j];
            }
#pragma unroll
            for (int i = 0; i < TM; ++i)
#pragma unroll
                for (int j = 0; j < TN; ++j) acc[i][j] += ar[i] * br[j];
        }
        __syncthreads();
    }
#pragma unroll
    for (int i = 0; i < TM; ++i) {
        int gm = r0 + ty * TM + i;
        if (gm >= M) continue;
#pragma unroll
        for (int j = 0; j < TN; ++j) {
            int gn = c0 + tx * TN + j;
            if (gn >= N) continue;
            float v = acc[i][j];
            if (add) v += add[(size_t)gm * ldc + gn];
            if (bias) v += bias[gn];
            if (relu) v = fmaxf(v, 0.f);
            C[(size_t)gm * ldc + gn] = v;
        }
    }
}

// ---------------- LSTM packs: gate-interleaved n = 4*unit + gate ----------------
__global__ void k_pack_wih(const float* __restrict__ Wih, float* __restrict__ o) {
    int idx = blockIdx.x * 256 + threadIdx.x;
    if (idx >= G4 * E) return;
    int k = idx % E;
    int n = idx / E;
    o[idx] = Wih[(size_t)((n & 3) * HH + (n >> 2)) * E + k];
}
__global__ void k_pack_whh(const float* __restrict__ Whh, float* __restrict__ o) {
    int idx = blockIdx.x * 256 + threadIdx.x;
    if (idx >= G4 * HH) return;
    int k = idx & 1023;
    int n = idx >> 10;
    o[idx] = Whh[(size_t)((n & 3) * HH + (n >> 2)) * HH + k];
}
__global__ void k_pack_b4i(const float* __restrict__ bih, const float* __restrict__ bhh,
                           float* __restrict__ out) {
    int n = blockIdx.x * 256 + threadIdx.x;
    if (n >= G4) return;
    int r = (n & 3) * HH + (n >> 2);
    out[n] = bih[r] + bhh[r];
}
__global__ void k_biasadd(const float* __restrict__ bih, const float* __restrict__ bhh,
                          float* __restrict__ out) {
    int idx = blockIdx.x * 256 + threadIdx.x;
    if (idx < G4) out[idx] = bih[idx] + bhh[idx];
}

// ---------------- plain cell (backward LSTM, natural gate layout i,f,g,o) ----------------
__global__ void k_cell_plain(float* __restrict__ h, float* __restrict__ c,
                             const float* __restrict__ gx, int first) {
    int idx = blockIdx.x * 256 + threadIdx.x;   // < BB*HH
    int b = idx >> 10, j = idx & 1023;
    size_t base = (size_t)b * G4 + j;
    float gi = gx[base], gf = gx[base + HH], gg = gx[base + 2 * HH], go = gx[base + 3 * HH];
    float cp = first ? 0.f : c[idx];
    float cn = sigm(gf) * cp + sigm(gi) * tanhf(gg);
    c[idx] = cn;
    h[idx] = sigm(go) * tanhf(cn);
}

// ---------------- LSTM step body: 512 blocks (16 rows x 64 cols), XCD-clustered --------
// h_out = (t even) ? hA : hB; h_in is the other buffer.
template <bool MULTI>
static __device__ __forceinline__ void lstm_body(
    const float* __restrict__ Xg, const float* __restrict__ Wpk,
    float* __restrict__ hA, float* __restrict__ hB, float* __restrict__ cb,
    int t0, int nsteps, int first_chunk) {
    __shared__ alignas(16) float As[16][20];
    __shared__ alignas(16) float Bs[16][68];
    const int tid = threadIdx.x;
    const int tx = tid & 15, ty = tid >> 4;
    const int id = blockIdx.x;
    const int xcd = id & 7, slot = id >> 3;
    const int cg2 = xcd * 8 + (slot >> 3);
    const int rb = slot & 7;
    const int r0 = rb * 16;
    const int c0 = cg2 * 64;
    const int ka = tid & 15, ma = tid >> 4;
    const int b = r0 + ty;
    const int jj4 = c0 + tx * 4;
    const int u = jj4 >> 2;
    const size_t ci = (size_t)b * HH + u;
    const float* wp0 = Wpk + (size_t)(c0 + ma) * HH + ka;

    for (int s = 0; s < nsteps; ++s) {
        const int t = t0 + s;
        const int first = (first_chunk && s == 0) ? 1 : 0;
        float acc[4] = {};
        if (!first) {
            const float* h_in = (t & 1) ? hA : hB;
            const float* hrow = h_in + (size_t)(r0 + ma) * HH + ka;
            float aA = hrow[0];
            float b0A = wp0[0], b1A = wp0[16 * HH], b2A = wp0[32 * HH], b3A = wp0[48 * HH];
            float aB = hrow[16];
            float b0B = wp0[16], b1B = wp0[16 * HH + 16], b2B = wp0[32 * HH + 16],
                  b3B = wp0[48 * HH + 16];
            for (int k0 = 0; k0 < HH; k0 += 16) {
                As[ka][ma] = aA;
                Bs[ka][ma] = b0A;
                Bs[ka][ma + 16] = b1A;
                Bs[ka][ma + 32] = b2A;
                Bs[ka][ma + 48] = b3A;
                __syncthreads();
                aA = aB; b0A = b0B; b1A = b1B; b2A = b2B; b3A = b3B;
                if (k0 + 32 < HH) {
                    int o = k0 + 32;
                    aB = hrow[o];
                    b0B = wp0[o];
                    b1B = wp0[16 * HH + o];
                    b2B = wp0[32 * HH + o];
                    b3B = wp0[48 * HH + o];
                }
#pragma unroll
                for (int k = 0; k < 16; ++k) {
                    float a = As[k][ty];
                    float4 b4 = *(const float4*)&Bs[k][tx * 4];
                    acc[0] += a * b4.x;
                    acc[1] += a * b4.y;
                    acc[2] += a * b4.z;
                    acc[3] += a * b4.w;
                }
                __syncthreads();
            }
        }
        float* h_out = (t & 1) ? hB : hA;
        float4 g4 = *(const float4*)&Xg[(size_t)s * BB * G4 + (size_t)b * G4 + jj4];
        float gi = acc[0] + g4.x;
        float gf = acc[1] + g4.y;
        float gg = acc[2] + g4.z;
        float go = acc[3] + g4.w;
        float cp = first ? 0.f : cb[ci];
        float cn = sigm(gf) * cp + sigm(gi) * tanhf(gg);
        cb[ci] = cn;
        h_out[ci] = sigm(go) * tanhf(cn);
        if constexpr (MULTI) cg::this_grid().sync();
    }
}

__global__ __launch_bounds__(256) void k_lstm_coop(
    const float* __restrict__ Xg, const float* __restrict__ Wpk,
    float* __restrict__ hA, float* __restrict__ hB, float* __restrict__ cb,
    int t0, int nsteps, int first_chunk) {
    lstm_body<true>(Xg, Wpk, hA, hB, cb, t0, nsteps, first_chunk);
}
__global__ __launch_bounds__(256) void k_lstm_fused(
    const float* __restrict__ Xg, const float* __restrict__ Wpk,
    float* __restrict__ hA, float* __restrict__ hB, float* __restrict__ cb,
    int t, int first) {
    lstm_body<false>(Xg, Wpk, hA, hB, cb, t, 1, first);
}

// ---------------- enc: l2norm(concat(hf, hb)) per batch row ----------------
__global__ void k_enc(const float* __restrict__ hf, const float* __restrict__ hb,
                      float* __restrict__ out) {
    int b = blockIdx.x;
    int tid = threadIdx.x;
    float vals[8];
    float ss = 0.f;
#pragma unroll
    for (int i = 0; i < 8; ++i) {
        int j = i * 256 + tid;
        float v = (j < HH) ? hf[(size_t)b * HH + j] : hb[(size_t)b * HH + (j - HH)];
        vals[i] = v;
        ss += v * v;
    }
    __shared__ float red[256];
    red[tid] = ss;
    __syncthreads();
    for (int s = 128; s > 0; s >>= 1) {
        if (tid < s) red[tid] += red[tid + s];
        __syncthreads();
    }
    float scale = 1.f / fmaxf(sqrtf(red[0]), 1e-12f);
#pragma unroll
    for (int i = 0; i < 8; ++i) out[(size_t)b * 2048 + i * 256 + tid] = vals[i] * scale;
}

// ---------------- per-pixel sum of squares over 1024 channels ----------------
__global__ void k_pixssq(const float* __restrict__ img, float* __restrict__ ssq) {
    int b = blockIdx.x >> 4;
    int cc = (blockIdx.x & 15) * 64;
    int p = threadIdx.x;
    if (p >= HW) return;
    const float* base = img + ((size_t)b * 1024 + cc) * HW + p;
    float acc = 0.f;
#pragma unroll 4
    for (int c = 0; c < 64; ++c) {
        float v = base[(size_t)c * HW];
        acc += v * v;
    }
    atomicAdd(&ssq[b * HW + p], acc);
}

// ---------------- weight packs: conv0 [ocg16][tap][k][8 oc]; conv_pm [ocg8][tap][k][16 oc] ----
__global__ void k_packB0(const float* __restrict__ w, float* __restrict__ o) {
    int idx = blockIdx.x * 256 + threadIdx.x;
    if (idx >= 16 * 9 * 1040 * 8) return;
    int oi = idx & 7;
    int r = idx >> 3;
    int c = r % 1040;
    int gt = r / 1040;
    int tap = gt % 9, ocg = gt / 9;
    o[idx] = (c < C0) ? w[((size_t)(ocg * 8 + oi) * C0 + c) * 9 + tap] : 0.f;
}
__global__ void k_packBpm(const float* __restrict__ w, float* __restrict__ o) {
    int idx = blockIdx.x * 256 + threadIdx.x;
    if (idx >= 8 * 9 * 128 * 16) return;
    int oi = idx & 15;
    int r = idx >> 4;
    int c = r % 128;
    int gt = r / 128;
    int tap = gt % 9, ocg = gt / 9;
    o[idx] = w[((size_t)(ocg * 16 + oi) * 128 + c) * 9 + tap];
}

// XCD-clustered swizzles
static __device__ __forceinline__ void conv_swz3136(int id, int& g, int& ocg, int& z) {
    int s2 = (id & 7) * 392 + (id >> 3);
    g = s2 >> 5;
    int cb = s2 & 31;
    ocg = cb >> 1;
    z = cb & 1;
}
static __device__ __forceinline__ void conv_swz1568(int id, int& g, int& ocg, int& z) {
    int s2 = (id & 7) * 196 + (id >> 3);
    g = s2 >> 4;
    int cb = s2 & 15;
    ocg = cb >> 1;
    z = cb & 1;
}

// ---------------- conv0: [k][pixel] LDS, K-step 8, 256-px tile, ocg=16 split ----------
// invn folded: reads raw ssq and computes 1/sqrt in per-block metadata.
__global__ __launch_bounds__(128) void k_conv0(const float* __restrict__ img,
                                               const float* __restrict__ ssq,
                                               const float* __restrict__ wpk,
                                               const float* __restrict__ bias,
                                               float* __restrict__ outParts) {
    __shared__ float As[8][292];   // [k][slot]; slot 288 forced zero
    const int tid = threadIdx.x;
    int g, ocg, z;
    conv_swz3136(blockIdx.x, g, ocg, z);
    const int kbeg = z ? 528 : 0;
    const int kend = z ? 1032 : 528;   // weights >=1026 are zero -> stop at 1032
    float* out = outParts + (size_t)z * NPX * CM;
    const int P0 = g * 256;
    const int gp1 = P0 + tid;
    const int gp2 = gp1 + 128;
    const int p1 = gp1 % HW, p2 = gp2 % HW;
    const int y1 = p1 / 14, x1 = p1 % 14;
    const int y2 = p2 / 14, x2 = p2 % 14;

    const float* sptr[3];
    float sinv[3], scy[3], scx[3];
#pragma unroll
    for (int j = 0; j < 3; ++j) {
        int s = tid + j * 128;
        int gp = P0 - 16 + s;
        bool ok = (s < 288) && (gp >= 0) && (gp < NPX);
        int gpc = ok ? gp : 0;
        int pp = gpc % HW;
        int bi = gpc / HW;
        sptr[j] = img + ((size_t)bi * 1024) * HW + pp;
        sinv[j] = ok ? (1.f / fmaxf(sqrtf(ssq[gpc]), 1e-12f)) : 0.f;
        scy[j] = ok ? (float)(pp / 14 - 7) * (1.f / 7.f) : 0.f;
        scx[j] = ok ? (float)(pp % 14 - 7) * (1.f / 7.f) : 0.f;
    }

    float acc0[8] = {};
    float acc1[8] = {};
    for (int k0 = kbeg; k0 < kend; k0 += 8) {
        __syncthreads();
        if (k0 != 1024) {
#pragma unroll
            for (int j = 0; j < 3; ++j) {
                int s = tid + j * 128;
                if (j < 2 || s < 292) {
                    const float* pb = sptr[j] + (size_t)k0 * HW;
                    float inv = sinv[j];
#pragma unroll
                    for (int k = 0; k < 8; ++k) As[k][s] = pb[(size_t)k * HW] * inv;
                }
            }
        } else {
#pragma unroll
            for (int j = 0; j < 3; ++j) {
                int s = tid + j * 128;
                if (j < 2 || s < 292) {
                    As[0][s] = scy[j];
                    As[1][s] = scx[j];
#pragma unroll
                    for (int k = 2; k < 8; ++k) As[k][s] = 0.f;
                }
            }
        }
        __syncthreads();
        for (int tap = 0; tap < 9; ++tap) {
            const int ky = tap / 3 - 1, kx = tap % 3 - 1;
            const int d = ky * 14 + kx;
            const int of1 = ((unsigned)(y1 + ky) < 14u && (unsigned)(x1 + kx) < 14u)
                                ? (tid + 16 + d) : 288;
            const int of2 = ((unsigned)(y2 + ky) < 14u && (unsigned)(x2 + kx) < 14u)
                                ? (tid + 144 + d) : 288;
            const float4* __restrict__ wq =
                (const float4*)wpk + ((size_t)(ocg * 9 + tap) * 1040 + k0) * 2;
#pragma unroll
            for (int k = 0; k < 8; ++k) {
                float a = As[k][of1];
                float b = As[k][of2];
                float4 w0 = wq[0], w1 = wq[1];
                wq += 2;
                acc0[0] += a * w0.x;  acc1[0] += b * w0.x;
                acc0[1] += a * w0.y;  acc1[1] += b * w0.y;
                acc0[2] += a * w0.z;  acc1[2] += b * w0.z;
                acc0[3] += a * w0.w;  acc1[3] += b * w0.w;
                acc0[4] += a * w1.x;  acc1[4] += b * w1.x;
                acc0[5] += a * w1.y;  acc1[5] += b * w1.y;
                acc0[6] += a * w1.z;  acc1[6] += b * w1.z;
                acc0[7] += a * w1.w;  acc1[7] += b * w1.w;
            }
        }
    }
    const float* bp = bias + ocg * 8;
    float* op1 = out + (size_t)gp1 * CM + ocg * 8;
    float* op2 = out + (size_t)gp2 * CM + ocg * 8;
#pragma unroll
    for (int qq = 0; qq < 2; ++qq) {
        float b0 = z ? 0.f : bp[qq * 4 + 0];
        float b1 = z ? 0.f : bp[qq * 4 + 1];
        float b2 = z ? 0.f : bp[qq * 4 + 2];
        float b3 = z ? 0.f : bp[qq * 4 + 3];
        float4 r0, r1;
        r0.x = acc0[qq * 4 + 0] + b0;  r1.x = acc1[qq * 4 + 0] + b0;
        r0.y = acc0[qq * 4 + 1] + b1;  r1.y = acc1[qq * 4 + 1] + b1;
        r0.z = acc0[qq * 4 + 2] + b2;  r1.z = acc1[qq * 4 + 2] + b2;
        r0.w = acc0[qq * 4 + 3] + b3;  r1.w = acc1[qq * 4 + 3] + b3;
        *(float4*)&op1[qq * 4] = r0;
        *(float4*)&op2[qq * 4] = r1;
    }
}

// ---------------- 3x3 pad1 conv, pixel-major [NPX][128], ocg=8 (16 oc), K-step 8 --------
__global__ __launch_bounds__(128) void k_conv_pm(const float* __restrict__ vin,
                                                 const float* __restrict__ wpk,
                                                 const float* __restrict__ bias,
                                                 float* __restrict__ outParts) {
    __shared__ float As[8][292];
    const int tid = threadIdx.x;
    int g, ocg, z;
    conv_swz1568(blockIdx.x, g, ocg, z);
    const int kbeg = z * 64;
    float* out = outParts + (size_t)z * NPX * CM;
    const int P0 = g * 256;
    const int gp1 = P0 + tid;
    const int gp2 = gp1 + 128;
    const int p1 = gp1 % HW, p2 = gp2 % HW;
    const int y1 = p1 / 14, x1 = p1 % 14;
    const int y2 = p2 / 14, x2 = p2 % 14;

    const float* sptr[3];
    float smask[3];
#pragma unroll
    for (int j = 0; j < 3; ++j) {
        int s = tid + j * 128;
        int gp = P0 - 16 + s;
        bool ok = (s < 288) && (gp >= 0) && (gp < NPX);
        sptr[j] = vin + (size_t)(ok ? gp : 0) * CM;
        smask[j] = ok ? 1.f : 0.f;
    }

    float acc0[16] = {};
    float acc1[16] = {};
    for (int k0 = kbeg; k0 < kbeg + 64; k0 += 8) {
        __syncthreads();
#pragma unroll
        for (int j = 0; j < 3; ++j) {
            int s = tid + j * 128;
            if (j < 2 || s < 292) {
                float4 v0 = *(const float4*)&sptr[j][k0];
                float4 v1 = *(const float4*)&sptr[j][k0 + 4];
                float m = smask[j];
                As[0][s] = v0.x * m;
                As[1][s] = v0.y * m;
                As[2][s] = v0.z * m;
                As[3][s] = v0.w * m;
                As[4][s] = v1.x * m;
                As[5][s] = v1.y * m;
                As[6][s] = v1.z * m;
                As[7][s] = v1.w * m;
            }
        }
        __syncthreads();
        for (int tap = 0; tap < 9; ++tap) {
            const int ky = tap / 3 - 1, kx = tap % 3 - 1;
            const int d = ky * 14 + kx;
            const int of1 = ((unsigned)(y1 + ky) < 14u && (unsigned)(x1 + kx) < 14u)
                                ? (tid + 16 + d) : 288;
            const int of2 = ((unsigned)(y2 + ky) < 14u && (unsigned)(x2 + kx) < 14u)
                                ? (tid + 144 + d) : 288;
            const float4* __restrict__ wq =
                (const float4*)wpk + ((size_t)(ocg * 9 + tap) * 128 + k0) * 4;
#pragma unroll
            for (int k = 0; k < 8; ++k) {
                float a = As[k][of1];
                float b = As[k][of2];
                float4 w0 = wq[0], w1 = wq[1], w2 = wq[2], w3 = wq[3];
                wq += 4;
                acc0[0]  += a * w0.x;  acc1[0]  += b * w0.x;
                acc0[1]  += a * w0.y;  acc1[1]  += b * w0.y;
                acc0[2]  += a * w0.z;  acc1[2]  += b * w0.z;
                acc0[3]  += a * w0.w;  acc1[3]  += b * w0.w;
                acc0[4]  += a * w1.x;  acc1[4]  += b * w1.x;
                acc0[5]  += a * w1.y;  acc1[5]  += b * w1.y;
                acc0[6]  += a * w1.z;  acc1[6]  += b * w1.z;
                acc0[7]  += a * w1.w;  acc1[7]  += b * w1.w;
                acc0[8]  += a * w2.x;  acc1[8]  += b * w2.x;
                acc0[9]  += a * w2.y;  acc1[9]  += b * w2.y;
                acc0[10] += a * w2.z;  acc1[10] += b * w2.z;
                acc0[11] += a * w2.w;  acc1[11] += b * w2.w;
                acc0[12] += a * w3.x;  acc1[12] += b * w3.x;
                acc0[13] += a * w3.y;  acc1[13] += b * w3.y;
                acc0[14] += a * w3.z;  acc1[14] += b * w3.z;
                acc0[15] += a * w3.w;  acc1[15] += b * w3.w;
            }
        }
    }
    const float* bp = bias + ocg * 16;
    float* op1 = out + (size_t)gp1 * CM + ocg * 16;
    float* op2 = out + (size_t)gp2 * CM + ocg * 16;
#pragma unroll
    for (int qq = 0; qq < 4; ++qq) {
        float b0 = z ? 0.f : bp[qq * 4 + 0];
        float b1 = z ? 0.f : bp[qq * 4 + 1];
        float b2 = z ? 0.f : bp[qq * 4 + 2];
        float b3 = z ? 0.f : bp[qq * 4 + 3];
        float4 r0, r1;
        r0.x = acc0[qq * 4 + 0] + b0;  r1.x = acc1[qq * 4 + 0] + b0;
        r0.y = acc0[qq * 4 + 1] + b1;  r1.y = acc1[qq * 4 + 1] + b1;
        r0.z = acc0[qq * 4 + 2] + b2;  r1.z = acc1[qq * 4 + 2] + b2;
        r0.w = acc0[qq * 4 + 3] + b3;  r1.w = acc1[qq * 4 + 3] + b3;
        *(float4*)&op1[qq * 4] = r0;
        *(float4*)&op2[qq * 4] = r1;
    }
}

// ---------------- BN train stats over 2 parts ----------------
__global__ void k_bnstats(const float* __restrict__ xa, const float* __restrict__ xb,
                          float* __restrict__ stats) {
    int r0 = blockIdx.x * 224;
    int c = threadIdx.x & 127, rh = threadIdx.x >> 7;
    float s = 0.f, ss = 0.f;
    for (int r = r0 + rh; r < r0 + 224; r += 2) {
        float v = xa[(size_t)r * CM + c] + xb[(size_t)r * CM + c];
        s += v;
        ss += v * v;
    }
    __shared__ float rs[256], rss[256];
    rs[threadIdx.x] = s;
    rss[threadIdx.x] = ss;
    __syncthreads();
    if (threadIdx.x < 128) {
        s = rs[threadIdx.x] + rs[threadIdx.x + 128];
        ss = rss[threadIdx.x] + rss[threadIdx.x + 128];
        atomicAdd(&stats[c], s);
        atomicAdd(&stats[128 + c], ss);
    }
}

// ---------------- relu(bn(xa+xb)) (+addv) -> vinr[p][c] (stride 130), BN-final inline ----
__global__ void k_apply_cat(const float* __restrict__ xa, const float* __restrict__ xb,
                            const float* __restrict__ stats,
                            const float* __restrict__ gg, const float* __restrict__ bb,
                            const float* __restrict__ addv, float* __restrict__ vinr) {
    int idx = blockIdx.x * 256 + threadIdx.x;
    if (idx >= NPX * CM) return;
    int c = idx & 127;
    int p = idx >> 7;
    float mean = stats[c] * (1.f / (float)NPX);
    float var = stats[128 + c] * (1.f / (float)NPX) - mean * mean;
    float sc = gg[c] * rsqrtf(var + 1e-5f);
    float sh = bb[c] - mean * sc;
    float v = fmaxf((xa[idx] + xb[idx]) * sc + sh, 0.f);
    if (addv) v += addv[idx];
    vinr[(size_t)p * CR + c] = v;
    if (c < 2) {
        int pp = p % HW;
        float cv = (c == 0) ? (float)(pp / 14 - 7) * (1.f / 7.f)
                            : (float)(pp % 14 - 7) * (1.f / 7.f);
        vinr[(size_t)p * CR + 128 + c] = cv;
    }
}

// ---------------- final: relu(bn(xa+xb)) + v1, transpose to NCHW, BN-final inline ----------
__global__ void k_final(const float* __restrict__ xa, const float* __restrict__ xb,
                        const float* __restrict__ stats,
                        const float* __restrict__ gg, const float* __restrict__ bb,
                        const float* __restrict__ addv, float* __restrict__ outv) {
    int idx = blockIdx.x * 256 + threadIdx.x;
    if (idx >= NPX * CM) return;
    int p = idx % HW;
    int o = (idx / HW) & 127;
    int b = idx / (HW * CM);
    float mean = stats[o] * (1.f / (float)NPX);
    float var = stats[128 + o] * (1.f / (float)NPX) - mean * mean;
    float sc = gg[o] * rsqrtf(var + 1e-5f);
    float sh = bb[o] - mean * sc;
    size_t pm = ((size_t)b * HW + p) * CM + o;
    outv[idx] = fmaxf((xa[pm] + xb[pm]) * sc + sh, 0.f) + addv[pm];
}

extern "C" void kernel_launch(void* const* d_in, const int* in_sizes, int n_in,
                              void* d_out, int out_size, void* d_ws, size_t ws_size,
                              hipStream_t stream) {
    const int* que = (const int*)d_in[0];
    const float* img = (const float*)d_in[1];
    const float* lookup = (const float*)d_in[2];
    const float* Wih_f = (const float*)d_in[3];
    const float* Whh_f = (const float*)d_in[4];
    const float* bih_f = (const float*)d_in[5];
    const float* bhh_f = (const float*)d_in[6];
    const float* Wih_b = (const float*)d_in[7];
    const float* bih_b = (const float*)d_in[9];
    const float* bhh_b = (const float*)d_in[10];
    const float* conv0_w = (const float*)d_in[11];
    const float* conv0_b = (const float*)d_in[12];
    const float* bn0_g = (const float*)d_in[13];
    const float* bn0_b = (const float*)d_in[14];
    const float* r1c1_w = (const float*)d_in[15];
    const float* r1c1_b = (const float*)d_in[16];
    const float* r1c2_w = (const float*)d_in[17];
    const float* r1c2_b = (const float*)d_in[18];
    const float* r1bn_g = (const float*)d_in[19];
    const float* r1bn_b = (const float*)d_in[20];
    const float* r2c1_w = (const float*)d_in[21];
    const float* r2c1_b = (const float*)d_in[22];
    const float* r2c2_w = (const float*)d_in[23];
    const float* r2c2_b = (const float*)d_in[24];
    const float* r2bn_g = (const float*)d_in[25];
    const float* r2bn_b = (const float*)d_in[26];
    float* out = (float*)d_out;

    float* ws = (float*)d_ws;
    // ---- LSTM region (dead after k_enc; image region overlays) ----
    float* emb = ws;                         // 1,728,000
    float* Xg = emb + 1728000;               // 7,864,320  (15 x 128 x 4096)
    float* WihPk = Xg + 7864320;             // 1,228,800  (4096 x 300)
    float* WhhPk = WihPk + 1228800;          // 4,194,304  (4096 x 1024)
    float* b4i = WhhPk + 4194304;            // 4,096
    float* b4b = b4i + 4096;                 // 4,096
    float* Xb = b4b + 4096;                  // 524,288
    float* hA = Xb + 524288;                 // 131,072
    float* hB = hA + 131072;                 // 131,072
    float* cbuf = hB + 131072;               // 131,072
    float* hbb = cbuf + 131072;              // 131,072
    size_t lstm_end = (size_t)(hbb + 131072 - ws);
    // ---- image region (overlays LSTM region) ----
    float* ssq = ws;                         // 25,088
    float* wpk0 = ssq + 25088;               // 1,198,080
    float* wpk1 = wpk0 + 1198080;            // 147,456
    float* wpk2 = wpk1 + 147456;             // 147,456
    float* xa = wpk2 + 147456;               // 3,211,264  (part 0)
    float* xb = xa + 3211264;                // 3,211,264  (part 1)
    float* vinr = xb + 3211264;              // 3,261,440
    float* v1 = vinr + 3261440;              // 3,211,264
    float* stats = v1 + 3211264;             // 256
    size_t img_end = (size_t)(stats + 256 - ws);
    size_t need = (lstm_end > img_end ? lstm_end : img_end) * 4;
    if (ws_size < need) return;

    auto cdiv = [](int a, int b) { return (a + b - 1) / b; };
    const size_t BG = (size_t)BB * G4;

    // ================= LSTM branch =================
    k_embed<<<cdiv(T * BB * E, 256), 256, 0, stream>>>(que, lookup, emb);
    k_pack_wih<<<cdiv(G4 * E, 256), 256, 0, stream>>>(Wih_f, WihPk);
    k_pack_whh<<<cdiv(G4 * HH, 256), 256, 0, stream>>>(Whh_f, WhhPk);
    k_pack_b4i<<<16, 256, 0, stream>>>(bih_f, bhh_f, b4i);
    k_biasadd<<<16, 256, 0, stream>>>(bih_b, bhh_b, b4b);
    // backward LSTM: only position T-1 used (natural layout)
    k_gemm_nt<64, 64, 4, 4><<<dim3(2, 64), 256, 0, stream>>>(
        emb + (size_t)(T - 1) * BB * E, E, Wih_b, E, nullptr, b4b, Xb, G4, BB, G4, E, 0);
    k_cell_plain<<<512, 256, 0, stream>>>(hbb, cbuf, Xb, 1);
    // forward LSTM: hoisted input gates (3 chunk GEMMs) + persistent coop chunk kernel
    int coop_ok = 1;
    for (int ch = 0; ch < 3; ++ch) {
        int t0 = ch * TCH;
        k_gemm_nt<64, 128, 4, 8><<<dim3(30, 32), 256, 0, stream>>>(
            emb + (size_t)t0 * BB * E, E, WihPk, E, nullptr, b4i, Xg, G4,
            TCH * BB, G4, E, 0);
        if (coop_ok) {
            int ns = TCH, fr = (ch == 0) ? 1 : 0;
            void* args[] = {(void*)&Xg, (void*)&WhhPk, (void*)&hA, (void*)&hB,
                            (void*)&cbuf, (void*)&t0, (void*)&ns, (void*)&fr};
            hipError_t e = hipLaunchCooperativeKernel(
                reinterpret_cast<void*>(k_lstm_coop), dim3(512), dim3(256, 1, 1),
                args, 0, stream);
            if (e != hipSuccess) coop_ok = 0;
        }
        if (!coop_ok) {
            for (int s = 0; s < TCH; ++s) {
                int t = t0 + s;
                k_lstm_fused<<<512, 256, 0, stream>>>(
                    Xg + (size_t)s * BG, WhhPk, hA, hB, cbuf, t, (t == 0) ? 1 : 0);
            }
        }
    }
    // t=44 (even) wrote hA
    k_enc<<<128, 256, 0, stream>>>(hA, hbb, out);

    // ================= image branch (reuses LSTM workspace) =================
    hipMemsetAsync(ssq, 0, NPX * 4, stream);
    k_pixssq<<<BB * 16, 256, 0, stream>>>(img, ssq);
    k_packB0<<<cdiv(16 * 9 * 1040 * 8, 256), 256, 0, stream>>>(conv0_w, wpk0);
    k_packBpm<<<cdiv(8 * 9 * 128 * 16, 256), 256, 0, stream>>>(r1c2_w, wpk1);
    k_packBpm<<<cdiv(8 * 9 * 128 * 16, 256), 256, 0, stream>>>(r2c2_w, wpk2);

    k_conv0<<<3136, 128, 0, stream>>>(img, ssq, wpk0, conv0_b, xa);
    hipMemsetAsync(stats, 0, 256 * 4, stream);
    k_bnstats<<<112, 256, 0, stream>>>(xa, xb, stats);
    k_apply_cat<<<cdiv(NPX * CM, 256), 256, 0, stream>>>(xa, xb, stats, bn0_g, bn0_b,
                                                         nullptr, vinr);

    // resblock 1 (1x1 conv as high-intensity GEMM)
    k_gemm_nt<128, 64, 8, 4><<<dim3(196, 2), 256, 0, stream>>>(
        vinr, CR, r1c1_w, CR, nullptr, r1c1_b, v1, CM, NPX, CM, CR, 1);
    k_conv_pm<<<1568, 128, 0, stream>>>(v1, wpk1, r1c2_b, xa);
    hipMemsetAsync(stats, 0, 256 * 4, stream);
    k_bnstats<<<112, 256, 0, stream>>>(xa, xb, stats);
    k_apply_cat<<<cdiv(NPX * CM, 256), 256, 0, stream>>>(xa, xb, stats, r1bn_g, r1bn_b,
                                                         v1, vinr);

    // resblock 2
    k_gemm_nt<128, 64, 8, 4><<<dim3(196, 2), 256, 0, stream>>>(
        vinr, CR, r2c1_w, CR, nullptr, r2c1_b, v1, CM, NPX, CM, CR, 1);
    k_conv_pm<<<1568, 128, 0, stream>>>(v1, wpk2, r2c2_b, xa);
    hipMemsetAsync(stats, 0, 256 * 4, stream);
    k_bnstats<<<112, 256, 0, stream>>>(xa, xb, stats);
    k_final<<<cdiv(NPX * CM, 256), 256, 0, stream>>>(xa, xb, stats, r2bn_g, r2bn_b,
                                                     v1, out + (size_t)BB * 2048);
}

// Round 15
// 3495.953 us; speedup vs baseline: 1.7374x; 1.7374x over previous
//
#include <hip/hip_runtime.h>
#include <math.h>

#define BB   128      // batch
#define T    45
#define E    300
#define HH   1024
#define G4   4096
#define HW   196      // 14*14
#define NPX  (BB*HW)  // 25088
#define C0   1026
#define CM   128
#define CR   130
#define TCH  15       // X-chunk timesteps (45 = 3*15)

static __device__ __forceinline__ float sigm(float x) { return 1.f / (1.f + __expf(-x)); }

// ---------------- embedding gather: emb[t][b][e] = lookup[que[b][t]][e] ----------------
__global__ void k_embed(const int* __restrict__ que, const float* __restrict__ lookup,
                        float* __restrict__ emb) {
    int idx = blockIdx.x * 256 + threadIdx.x;
    if (idx >= T * BB * E) return;
    int e = idx % E;
    int n = idx / E;
    int b = n % BB;
    int t = n / BB;
    int q = que[b * T + t];
    emb[idx] = lookup[(size_t)q * E + e];
}

// ---------------- generic NT GEMM: C[m][n] = sum A[m][k]*Bw[n][k] (+add)(+bias)(relu) ----
template <int BM, int BN, int TM, int TN>
__global__ __launch_bounds__(256) void k_gemm_nt(
    const float* __restrict__ A, int lda,
    const float* __restrict__ Bw, int ldb,
    const float* __restrict__ add,
    const float* __restrict__ bias,
    float* __restrict__ C, int ldc,
    int M, int N, int K, int relu) {
    constexpr int KT = 16;
    constexpr int TX = BN / TN;
    __shared__ alignas(16) float As[KT][BM + 4];
    __shared__ alignas(16) float Bs[KT][BN + 4];
    const int tid = threadIdx.x;
    const int tx = tid % TX, ty = tid / TX;
    const int r0 = blockIdx.x * BM, c0 = blockIdx.y * BN;
    float acc[TM][TN] = {};
    for (int k0 = 0; k0 < K; k0 += KT) {
#pragma unroll
        for (int l = tid; l < BM * KT; l += 256) {
            int m = l / KT, k = l % KT;
            int gm = r0 + m, gk = k0 + k;
            As[k][m] = (gm < M && gk < K) ? A[(size_t)gm * lda + gk] : 0.f;
        }
#pragma unroll
        for (int l = tid; l < BN * KT; l += 256) {
            int n = l / KT, k = l % KT;
            int gn = c0 + n, gk = k0 + k;
            Bs[k][n] = (gn < N && gk < K) ? Bw[(size_t)gn * ldb + gk] : 0.f;
        }
        __syncthreads();
#pragma unroll
        for (int k = 0; k < KT; ++k) {
            float ar[TM], br[TN];
            if constexpr ((TM & 3) == 0) {
#pragma unroll
                for (int i = 0; i < TM; i += 4) {
                    float4 v = *(const float4*)&As[k][ty * TM + i];
                    ar[i] = v.x; ar[i + 1] = v.y; ar[i + 2] = v.z; ar[i + 3] = v.w;
                }
            } else if constexpr ((TM & 1) == 0) {
#pragma unroll
                for (int i = 0; i < TM; i += 2) {
                    float2 v = *(const float2*)&As[k][ty * TM + i];
                    ar[i] = v.x; ar[i + 1] = v.y;
                }
            } else {
#pragma unroll
                for (int i = 0; i < TM; ++i) ar[i] = As[k][ty * TM + i];
            }
            if constexpr ((TN & 3) == 0) {
#pragma unroll
                for (int j = 0; j < TN; j += 4) {
                    float4 v = *(const float4*)&Bs[k][tx * TN + j];
                    br[j] = v.x; br[j + 1] = v.y; br[j + 2] = v.z; br[j + 3] = v.w;
                }
            } else if constexpr ((TN & 1) == 0) {
#pragma unroll
                for (int j = 0; j < TN; j += 2) {
                    float2 v = *(const float2*)&Bs[k][tx * TN + j];
                    br[j] = v.x; br[j + 1] = v.y;
                }
            } else {
#pragma unroll
                for (int j = 0; j < TN; ++j) br[j] = Bs[k][tx * TN + j];
            }
#pragma unroll
            for (int i = 0; i < TM; ++i)
#pragma unroll
                for (int j = 0; j < TN; ++j) acc[i][j] += ar[i] * br[j];
        }
        __syncthreads();
    }
#pragma unroll
    for (int i = 0; i < TM; ++i) {
        int gm = r0 + ty * TM + i;
        if (gm >= M) continue;
#pragma unroll
        for (int j = 0; j < TN; ++j) {
            int gn = c0 + tx * TN + j;
            if (gn >= N) continue;
            float v = acc[i][j];
            if (add) v += add[(size_t)gm * ldc + gn];
            if (bias) v += bias[gn];
            if (relu) v = fmaxf(v, 0.f);
            C[(size_t)gm * ldc + gn] = v;
        }
    }
}

// ---------------- LSTM packs: gate-interleaved n = 4*unit + gate ----------------
__global__ void k_pack_wih(const float* __restrict__ Wih, float* __restrict__ o) {
    int idx = blockIdx.x * 256 + threadIdx.x;
    if (idx >= G4 * E) return;
    int k = idx % E;
    int n = idx / E;
    o[idx] = Wih[(size_t)((n & 3) * HH + (n >> 2)) * E + k];
}
__global__ void k_pack_whh(const float* __restrict__ Whh, float* __restrict__ o) {
    int idx = blockIdx.x * 256 + threadIdx.x;
    if (idx >= G4 * HH) return;
    int k = idx & 1023;
    int n = idx >> 10;
    o[idx] = Whh[(size_t)((n & 3) * HH + (n >> 2)) * HH + k];
}
__global__ void k_pack_b4i(const float* __restrict__ bih, const float* __restrict__ bhh,
                           float* __restrict__ out) {
    int n = blockIdx.x * 256 + threadIdx.x;
    if (n >= G4) return;
    int r = (n & 3) * HH + (n >> 2);
    out[n] = bih[r] + bhh[r];
}
__global__ void k_biasadd(const float* __restrict__ bih, const float* __restrict__ bhh,
                          float* __restrict__ out) {
    int idx = blockIdx.x * 256 + threadIdx.x;
    if (idx < G4) out[idx] = bih[idx] + bhh[idx];
}

// ---------------- plain cell (backward LSTM, natural gate layout i,f,g,o) ----------------
__global__ void k_cell_plain(float* __restrict__ h, float* __restrict__ c,
                             const float* __restrict__ gx, int first) {
    int idx = blockIdx.x * 256 + threadIdx.x;   // < BB*HH
    int b = idx >> 10, j = idx & 1023;
    size_t base = (size_t)b * G4 + j;
    float gi = gx[base], gf = gx[base + HH], gg = gx[base + 2 * HH], go = gx[base + 3 * HH];
    float cp = first ? 0.f : c[idx];
    float cn = sigm(gf) * cp + sigm(gi) * tanhf(gg);
    c[idx] = cn;
    h[idx] = sigm(go) * tanhf(cn);
}

// ---------------- fused LSTM recurrent step: acc = h @ WhhPk^T; gates = acc + gx --------
// 512 blocks (16 rows x 64 cols each) = 2 blocks/CU; XCD-clustered so each XCD touches
// only its 8 column-groups' weights (2MB). 2-deep register prefetch.
__global__ __launch_bounds__(256) void k_lstm_fused(
    const float* __restrict__ h_in, float* __restrict__ c_io,
    const float* __restrict__ gx,
    const float* __restrict__ Wpk,
    float* __restrict__ h_out, int first) {
    __shared__ alignas(16) float As[16][20];
    __shared__ alignas(16) float Bs[16][68];
    const int tid = threadIdx.x;
    const int tx = tid & 15, ty = tid >> 4;
    const int id = blockIdx.x;
    const int xcd = id & 7, slot = id >> 3;       // 64 slots per XCD
    const int cg = xcd * 8 + (slot >> 3);         // column-group 0..63 (64 cols each)
    const int rb = slot & 7;                      // row-block 0..7 (16 rows each)
    const int r0 = rb * 16;
    const int c0 = cg * 64;
    const int ka = tid & 15, ma = tid >> 4;
    float acc[4] = {};

    if (!first) {
        const float* hrow = h_in + (size_t)(r0 + ma) * HH + ka;
        const float* wp0 = Wpk + (size_t)(c0 + ma) * HH + ka;
        float aA = hrow[0];
        float b0A = wp0[0], b1A = wp0[16 * HH], b2A = wp0[32 * HH], b3A = wp0[48 * HH];
        float aB = hrow[16];
        float b0B = wp0[16], b1B = wp0[16 * HH + 16], b2B = wp0[32 * HH + 16],
              b3B = wp0[48 * HH + 16];
        for (int k0 = 0; k0 < HH; k0 += 16) {
            As[ka][ma] = aA;
            Bs[ka][ma] = b0A;
            Bs[ka][ma + 16] = b1A;
            Bs[ka][ma + 32] = b2A;
            Bs[ka][ma + 48] = b3A;
            __syncthreads();
            aA = aB; b0A = b0B; b1A = b1B; b2A = b2B; b3A = b3B;
            if (k0 + 32 < HH) {
                int o = k0 + 32;
                aB = hrow[o];
                b0B = wp0[o];
                b1B = wp0[16 * HH + o];
                b2B = wp0[32 * HH + o];
                b3B = wp0[48 * HH + o];
            }
#pragma unroll
            for (int k = 0; k < 16; ++k) {
                float a = As[k][ty];
                float4 b4 = *(const float4*)&Bs[k][tx * 4];
                acc[0] += a * b4.x;
                acc[1] += a * b4.y;
                acc[2] += a * b4.z;
                acc[3] += a * b4.w;
            }
            __syncthreads();
        }
    }
    const int b = r0 + ty;
    const int jj4 = c0 + tx * 4;    // 4 consecutive packed cols = one unit's i,f,g,o
    const int u = jj4 >> 2;
    float4 g4 = *(const float4*)&gx[(size_t)b * G4 + jj4];
    float gi = acc[0] + g4.x;
    float gf = acc[1] + g4.y;
    float gg = acc[2] + g4.z;
    float go = acc[3] + g4.w;
    size_t ci = (size_t)b * HH + u;
    float cp = first ? 0.f : c_io[ci];
    float cn = sigm(gf) * cp + sigm(gi) * tanhf(gg);
    c_io[ci] = cn;
    h_out[ci] = sigm(go) * tanhf(cn);
}

// ---------------- enc: l2norm(concat(hf, hb)) per batch row ----------------
__global__ void k_enc(const float* __restrict__ hf, const float* __restrict__ hb,
                      float* __restrict__ out) {
    int b = blockIdx.x;
    int tid = threadIdx.x;
    float vals[8];
    float ss = 0.f;
#pragma unroll
    for (int i = 0; i < 8; ++i) {
        int j = i * 256 + tid;
        float v = (j < HH) ? hf[(size_t)b * HH + j] : hb[(size_t)b * HH + (j - HH)];
        vals[i] = v;
        ss += v * v;
    }
    __shared__ float red[256];
    red[tid] = ss;
    __syncthreads();
    for (int s = 128; s > 0; s >>= 1) {
        if (tid < s) red[tid] += red[tid + s];
        __syncthreads();
    }
    float scale = 1.f / fmaxf(sqrtf(red[0]), 1e-12f);
#pragma unroll
    for (int i = 0; i < 8; ++i) out[(size_t)b * 2048 + i * 256 + tid] = vals[i] * scale;
}

// ---------------- per-pixel sum of squares over 1024 channels ----------------
__global__ void k_pixssq(const float* __restrict__ img, float* __restrict__ ssq) {
    int b = blockIdx.x >> 4;
    int cc = (blockIdx.x & 15) * 64;
    int p = threadIdx.x;
    if (p >= HW) return;
    const float* base = img + ((size_t)b * 1024 + cc) * HW + p;
    float acc = 0.f;
#pragma unroll 4
    for (int c = 0; c < 64; ++c) {
        float v = base[(size_t)c * HW];
        acc += v * v;
    }
    atomicAdd(&ssq[b * HW + p], acc);
}

// ---------------- weight packs: conv0 [ocg16][tap][k][8 oc]; conv_pm [ocg8][tap][k][16 oc] ----
__global__ void k_packB0(const float* __restrict__ w, float* __restrict__ o) {
    int idx = blockIdx.x * 256 + threadIdx.x;
    if (idx >= 16 * 9 * 1040 * 8) return;
    int oi = idx & 7;
    int r = idx >> 3;
    int c = r % 1040;
    int gt = r / 1040;
    int tap = gt % 9, ocg = gt / 9;
    o[idx] = (c < C0) ? w[((size_t)(ocg * 8 + oi) * C0 + c) * 9 + tap] : 0.f;
}
__global__ void k_packBpm(const float* __restrict__ w, float* __restrict__ o) {
    int idx = blockIdx.x * 256 + threadIdx.x;
    if (idx >= 8 * 9 * 128 * 16) return;
    int oi = idx & 15;
    int r = idx >> 4;
    int c = r % 128;
    int gt = r / 128;
    int tap = gt % 9, ocg = gt / 9;
    o[idx] = w[((size_t)(ocg * 16 + oi) * 128 + c) * 9 + tap];
}

// XCD-clustered swizzles
static __device__ __forceinline__ void conv_swz3136(int id, int& g, int& ocg, int& z) {
    int s2 = (id & 7) * 392 + (id >> 3);
    g = s2 >> 5;
    int cb = s2 & 31;
    ocg = cb >> 1;
    z = cb & 1;
}
static __device__ __forceinline__ void conv_swz1568(int id, int& g, int& ocg, int& z) {
    int s2 = (id & 7) * 196 + (id >> 3);
    g = s2 >> 4;
    int cb = s2 & 15;
    ocg = cb >> 1;
    z = cb & 1;
}

// ---------------- conv0: [k][pixel] LDS, K-step 8, 256-px tile, ocg=16 split ----------
// invn folded: reads raw ssq and computes 1/sqrt in per-block metadata.
__global__ __launch_bounds__(128) void k_conv0(const float* __restrict__ img,
                                               const float* __restrict__ ssq,
                                               const float* __restrict__ wpk,
                                               const float* __restrict__ bias,
                                               float* __restrict__ outParts) {
    __shared__ float As[8][292];   // [k][slot]; slot 288 forced zero
    const int tid = threadIdx.x;
    int g, ocg, z;
    conv_swz3136(blockIdx.x, g, ocg, z);
    const int kbeg = z ? 528 : 0;
    const int kend = z ? 1032 : 528;   // weights >=1026 are zero -> stop at 1032
    float* out = outParts + (size_t)z * NPX * CM;
    const int P0 = g * 256;
    const int gp1 = P0 + tid;
    const int gp2 = gp1 + 128;
    const int p1 = gp1 % HW, p2 = gp2 % HW;
    const int y1 = p1 / 14, x1 = p1 % 14;
    const int y2 = p2 / 14, x2 = p2 % 14;

    const float* sptr[3];
    float sinv[3], scy[3], scx[3];
#pragma unroll
    for (int j = 0; j < 3; ++j) {
        int s = tid + j * 128;
        int gp = P0 - 16 + s;
        bool ok = (s < 288) && (gp >= 0) && (gp < NPX);
        int gpc = ok ? gp : 0;
        int pp = gpc % HW;
        int bi = gpc / HW;
        sptr[j] = img + ((size_t)bi * 1024) * HW + pp;
        sinv[j] = ok ? (1.f / fmaxf(sqrtf(ssq[gpc]), 1e-12f)) : 0.f;
        scy[j] = ok ? (float)(pp / 14 - 7) * (1.f / 7.f) : 0.f;
        scx[j] = ok ? (float)(pp % 14 - 7) * (1.f / 7.f) : 0.f;
    }

    float acc0[8] = {};
    float acc1[8] = {};
    for (int k0 = kbeg; k0 < kend; k0 += 8) {
        __syncthreads();
        if (k0 != 1024) {
#pragma unroll
            for (int j = 0; j < 3; ++j) {
                int s = tid + j * 128;
                if (j < 2 || s < 292) {
                    const float* pb = sptr[j] + (size_t)k0 * HW;
                    float inv = sinv[j];
#pragma unroll
                    for (int k = 0; k < 8; ++k) As[k][s] = pb[(size_t)k * HW] * inv;
                }
            }
        } else {
#pragma unroll
            for (int j = 0; j < 3; ++j) {
                int s = tid + j * 128;
                if (j < 2 || s < 292) {
                    As[0][s] = scy[j];
                    As[1][s] = scx[j];
#pragma unroll
                    for (int k = 2; k < 8; ++k) As[k][s] = 0.f;
                }
            }
        }
        __syncthreads();
        for (int tap = 0; tap < 9; ++tap) {
            const int ky = tap / 3 - 1, kx = tap % 3 - 1;
            const int d = ky * 14 + kx;
            const int of1 = ((unsigned)(y1 + ky) < 14u && (unsigned)(x1 + kx) < 14u)
                                ? (tid + 16 + d) : 288;
            const int of2 = ((unsigned)(y2 + ky) < 14u && (unsigned)(x2 + kx) < 14u)
                                ? (tid + 144 + d) : 288;
            const float4* __restrict__ wq =
                (const float4*)wpk + ((size_t)(ocg * 9 + tap) * 1040 + k0) * 2;
#pragma unroll
            for (int k = 0; k < 8; ++k) {
                float a = As[k][of1];
                float b = As[k][of2];
                float4 w0 = wq[0], w1 = wq[1];
                wq += 2;
                acc0[0] += a * w0.x;  acc1[0] += b * w0.x;
                acc0[1] += a * w0.y;  acc1[1] += b * w0.y;
                acc0[2] += a * w0.z;  acc1[2] += b * w0.z;
                acc0[3] += a * w0.w;  acc1[3] += b * w0.w;
                acc0[4] += a * w1.x;  acc1[4] += b * w1.x;
                acc0[5] += a * w1.y;  acc1[5] += b * w1.y;
                acc0[6] += a * w1.z;  acc1[6] += b * w1.z;
                acc0[7] += a * w1.w;  acc1[7] += b * w1.w;
            }
        }
    }
    const float* bp = bias + ocg * 8;
    float* op1 = out + (size_t)gp1 * CM + ocg * 8;
    float* op2 = out + (size_t)gp2 * CM + ocg * 8;
#pragma unroll
    for (int qq = 0; qq < 2; ++qq) {
        float b0 = z ? 0.f : bp[qq * 4 + 0];
        float b1 = z ? 0.f : bp[qq * 4 + 1];
        float b2 = z ? 0.f : bp[qq * 4 + 2];
        float b3 = z ? 0.f : bp[qq * 4 + 3];
        float4 r0, r1;
        r0.x = acc0[qq * 4 + 0] + b0;  r1.x = acc1[qq * 4 + 0] + b0;
        r0.y = acc0[qq * 4 + 1] + b1;  r1.y = acc1[qq * 4 + 1] + b1;
        r0.z = acc0[qq * 4 + 2] + b2;  r1.z = acc1[qq * 4 + 2] + b2;
        r0.w = acc0[qq * 4 + 3] + b3;  r1.w = acc1[qq * 4 + 3] + b3;
        *(float4*)&op1[qq * 4] = r0;
        *(float4*)&op2[qq * 4] = r1;
    }
}

// ---------------- 3x3 pad1 conv, pixel-major [NPX][128], ocg=8 (16 oc), K-step 8 --------
__global__ __launch_bounds__(128) void k_conv_pm(const float* __restrict__ vin,
                                                 const float* __restrict__ wpk,
                                                 const float* __restrict__ bias,
                                                 float* __restrict__ outParts) {
    __shared__ float As[8][292];
    const int tid = threadIdx.x;
    int g, ocg, z;
    conv_swz1568(blockIdx.x, g, ocg, z);
    const int kbeg = z * 64;
    float* out = outParts + (size_t)z * NPX * CM;
    const int P0 = g * 256;
    const int gp1 = P0 + tid;
    const int gp2 = gp1 + 128;
    const int p1 = gp1 % HW, p2 = gp2 % HW;
    const int y1 = p1 / 14, x1 = p1 % 14;
    const int y2 = p2 / 14, x2 = p2 % 14;

    const float* sptr[3];
    float smask[3];
#pragma unroll
    for (int j = 0; j < 3; ++j) {
        int s = tid + j * 128;
        int gp = P0 - 16 + s;
        bool ok = (s < 288) && (gp >= 0) && (gp < NPX);
        sptr[j] = vin + (size_t)(ok ? gp : 0) * CM;
        smask[j] = ok ? 1.f : 0.f;
    }

    float acc0[16] = {};
    float acc1[16] = {};
    for (int k0 = kbeg; k0 < kbeg + 64; k0 += 8) {
        __syncthreads();
#pragma unroll
        for (int j = 0; j < 3; ++j) {
            int s = tid + j * 128;
            if (j < 2 || s < 292) {
                float4 v0 = *(const float4*)&sptr[j][k0];
                float4 v1 = *(const float4*)&sptr[j][k0 + 4];
                float m = smask[j];
                As[0][s] = v0.x * m;
                As[1][s] = v0.y * m;
                As[2][s] = v0.z * m;
                As[3][s] = v0.w * m;
                As[4][s] = v1.x * m;
                As[5][s] = v1.y * m;
                As[6][s] = v1.z * m;
                As[7][s] = v1.w * m;
            }
        }
        __syncthreads();
        for (int tap = 0; tap < 9; ++tap) {
            const int ky = tap / 3 - 1, kx = tap % 3 - 1;
            const int d = ky * 14 + kx;
            const int of1 = ((unsigned)(y1 + ky) < 14u && (unsigned)(x1 + kx) < 14u)
                                ? (tid + 16 + d) : 288;
            const int of2 = ((unsigned)(y2 + ky) < 14u && (unsigned)(x2 + kx) < 14u)
                                ? (tid + 144 + d) : 288;
            const float4* __restrict__ wq =
                (const float4*)wpk + ((size_t)(ocg * 9 + tap) * 128 + k0) * 4;
#pragma unroll
            for (int k = 0; k < 8; ++k) {
                float a = As[k][of1];
                float b = As[k][of2];
                float4 w0 = wq[0], w1 = wq[1], w2 = wq[2], w3 = wq[3];
                wq += 4;
                acc0[0]  += a * w0.x;  acc1[0]  += b * w0.x;
                acc0[1]  += a * w0.y;  acc1[1]  += b * w0.y;
                acc0[2]  += a * w0.z;  acc1[2]  += b * w0.z;
                acc0[3]  += a * w0.w;  acc1[3]  += b * w0.w;
                acc0[4]  += a * w1.x;  acc1[4]  += b * w1.x;
                acc0[5]  += a * w1.y;  acc1[5]  += b * w1.y;
                acc0[6]  += a * w1.z;  acc1[6]  += b * w1.z;
                acc0[7]  += a * w1.w;  acc1[7]  += b * w1.w;
                acc0[8]  += a * w2.x;  acc1[8]  += b * w2.x;
                acc0[9]  += a * w2.y;  acc1[9]  += b * w2.y;
                acc0[10] += a * w2.z;  acc1[10] += b * w2.z;
                acc0[11] += a * w2.w;  acc1[11] += b * w2.w;
                acc0[12] += a * w3.x;  acc1[12] += b * w3.x;
                acc0[13] += a * w3.y;  acc1[13] += b * w3.y;
                acc0[14] += a * w3.z;  acc1[14] += b * w3.z;
                acc0[15] += a * w3.w;  acc1[15] += b * w3.w;
            }
        }
    }
    const float* bp = bias + ocg * 16;
    float* op1 = out + (size_t)gp1 * CM + ocg * 16;
    float* op2 = out + (size_t)gp2 * CM + ocg * 16;
#pragma unroll
    for (int qq = 0; qq < 4; ++qq) {
        float b0 = z ? 0.f : bp[qq * 4 + 0];
        float b1 = z ? 0.f : bp[qq * 4 + 1];
        float b2 = z ? 0.f : bp[qq * 4 + 2];
        float b3 = z ? 0.f : bp[qq * 4 + 3];
        float4 r0, r1;
        r0.x = acc0[qq * 4 + 0] + b0;  r1.x = acc1[qq * 4 + 0] + b0;
        r0.y = acc0[qq * 4 + 1] + b1;  r1.y = acc1[qq * 4 + 1] + b1;
        r0.z = acc0[qq * 4 + 2] + b2;  r1.z = acc1[qq * 4 + 2] + b2;
        r0.w = acc0[qq * 4 + 3] + b3;  r1.w = acc1[qq * 4 + 3] + b3;
        *(float4*)&op1[qq * 4] = r0;
        *(float4*)&op2[qq * 4] = r1;
    }
}

// ---------------- BN train stats over 2 parts ----------------
__global__ void k_bnstats(const float* __restrict__ xa, const float* __restrict__ xb,
                          float* __restrict__ stats) {
    int r0 = blockIdx.x * 224;
    int c = threadIdx.x & 127, rh = threadIdx.x >> 7;
    float s = 0.f, ss = 0.f;
    for (int r = r0 + rh; r < r0 + 224; r += 2) {
        float v = xa[(size_t)r * CM + c] + xb[(size_t)r * CM + c];
        s += v;
        ss += v * v;
    }
    __shared__ float rs[256], rss[256];
    rs[threadIdx.x] = s;
    rss[threadIdx.x] = ss;
    __syncthreads();
    if (threadIdx.x < 128) {
        s = rs[threadIdx.x] + rs[threadIdx.x + 128];
        ss = rss[threadIdx.x] + rss[threadIdx.x + 128];
        atomicAdd(&stats[c], s);
        atomicAdd(&stats[128 + c], ss);
    }
}

// ---------------- relu(bn(xa+xb)) (+addv) -> vinr[p][c] (stride 130), BN-final inline ----
__global__ void k_apply_cat(const float* __restrict__ xa, const float* __restrict__ xb,
                            const float* __restrict__ stats,
                            const float* __restrict__ gg, const float* __restrict__ bb,
                            const float* __restrict__ addv, float* __restrict__ vinr) {
    int idx = blockIdx.x * 256 + threadIdx.x;
    if (idx >= NPX * CM) return;
    int c = idx & 127;
    int p = idx >> 7;
    float mean = stats[c] * (1.f / (float)NPX);
    float var = stats[128 + c] * (1.f / (float)NPX) - mean * mean;
    float sc = gg[c] * rsqrtf(var + 1e-5f);
    float sh = bb[c] - mean * sc;
    float v = fmaxf((xa[idx] + xb[idx]) * sc + sh, 0.f);
    if (addv) v += addv[idx];
    vinr[(size_t)p * CR + c] = v;
    if (c < 2) {
        int pp = p % HW;
        float cv = (c == 0) ? (float)(pp / 14 - 7) * (1.f / 7.f)
                            : (float)(pp % 14 - 7) * (1.f / 7.f);
        vinr[(size_t)p * CR + 128 + c] = cv;
    }
}

// ---------------- final: relu(bn(xa+xb)) + v1, transpose to NCHW, BN-final inline ----------
__global__ void k_final(const float* __restrict__ xa, const float* __restrict__ xb,
                        const float* __restrict__ stats,
                        const float* __restrict__ gg, const float* __restrict__ bb,
                        const float* __restrict__ addv, float* __restrict__ outv) {
    int idx = blockIdx.x * 256 + threadIdx.x;
    if (idx >= NPX * CM) return;
    int p = idx % HW;
    int o = (idx / HW) & 127;
    int b = idx / (HW * CM);
    float mean = stats[o] * (1.f / (float)NPX);
    float var = stats[128 + o] * (1.f / (float)NPX) - mean * mean;
    float sc = gg[o] * rsqrtf(var + 1e-5f);
    float sh = bb[o] - mean * sc;
    size_t pm = ((size_t)b * HW + p) * CM + o;
    outv[idx] = fmaxf((xa[pm] + xb[pm]) * sc + sh, 0.f) + addv[pm];
}

extern "C" void kernel_launch(void* const* d_in, const int* in_sizes, int n_in,
                              void* d_out, int out_size, void* d_ws, size_t ws_size,
                              hipStream_t stream) {
    const int* que = (const int*)d_in[0];
    const float* img = (const float*)d_in[1];
    const float* lookup = (const float*)d_in[2];
    const float* Wih_f = (const float*)d_in[3];
    const float* Whh_f = (const float*)d_in[4];
    const float* bih_f = (const float*)d_in[5];
    const float* bhh_f = (const float*)d_in[6];
    const float* Wih_b = (const float*)d_in[7];
    const float* bih_b = (const float*)d_in[9];
    const float* bhh_b = (const float*)d_in[10];
    const float* conv0_w = (const float*)d_in[11];
    const float* conv0_b = (const float*)d_in[12];
    const float* bn0_g = (const float*)d_in[13];
    const float* bn0_b = (const float*)d_in[14];
    const float* r1c1_w = (const float*)d_in[15];
    const float* r1c1_b = (const float*)d_in[16];
    const float* r1c2_w = (const float*)d_in[17];
    const float* r1c2_b = (const float*)d_in[18];
    const float* r1bn_g = (const float*)d_in[19];
    const float* r1bn_b = (const float*)d_in[20];
    const float* r2c1_w = (const float*)d_in[21];
    const float* r2c1_b = (const float*)d_in[22];
    const float* r2c2_w = (const float*)d_in[23];
    const float* r2c2_b = (const float*)d_in[24];
    const float* r2bn_g = (const float*)d_in[25];
    const float* r2bn_b = (const float*)d_in[26];
    float* out = (float*)d_out;

    float* ws = (float*)d_ws;
    // ---- LSTM region (dead after k_enc; image region overlays) ----
    float* emb = ws;                         // 1,728,000
    float* Xg = emb + 1728000;               // 7,864,320  (15 x 128 x 4096)
    float* WihPk = Xg + 7864320;             // 1,228,800  (4096 x 300)
    float* WhhPk = WihPk + 1228800;          // 4,194,304  (4096 x 1024)
    float* b4i = WhhPk + 4194304;            // 4,096
    float* b4b = b4i + 4096;                 // 4,096
    float* Xb = b4b + 4096;                  // 524,288
    float* hA = Xb + 524288;                 // 131,072
    float* hB = hA + 131072;                 // 131,072
    float* cbuf = hB + 131072;               // 131,072
    float* hbb = cbuf + 131072;              // 131,072
    size_t lstm_end = (size_t)(hbb + 131072 - ws);
    // ---- image region (overlays LSTM region) ----
    float* ssq = ws;                         // 25,088
    float* wpk0 = ssq + 25088;               // 1,198,080
    float* wpk1 = wpk0 + 1198080;            // 147,456
    float* wpk2 = wpk1 + 147456;             // 147,456
    float* xa = wpk2 + 147456;               // 3,211,264  (part 0)
    float* xb = xa + 3211264;                // 3,211,264  (part 1)
    float* vinr = xb + 3211264;              // 3,261,440
    float* v1 = vinr + 3261440;              // 3,211,264
    float* stats = v1 + 3211264;             // 256
    size_t img_end = (size_t)(stats + 256 - ws);
    size_t need = (lstm_end > img_end ? lstm_end : img_end) * 4;
    if (ws_size < need) return;

    auto cdiv = [](int a, int b) { return (a + b - 1) / b; };
    const size_t BG = (size_t)BB * G4;

    // ================= LSTM branch =================
    k_embed<<<cdiv(T * BB * E, 256), 256, 0, stream>>>(que, lookup, emb);
    k_pack_wih<<<cdiv(G4 * E, 256), 256, 0, stream>>>(Wih_f, WihPk);
    k_pack_whh<<<cdiv(G4 * HH, 256), 256, 0, stream>>>(Whh_f, WhhPk);
    k_pack_b4i<<<16, 256, 0, stream>>>(bih_f, bhh_f, b4i);
    k_biasadd<<<16, 256, 0, stream>>>(bih_b, bhh_b, b4b);
    // backward LSTM: only position T-1 used (natural layout)
    k_gemm_nt<64, 64, 4, 4><<<dim3(2, 64), 256, 0, stream>>>(
        emb + (size_t)(T - 1) * BB * E, E, Wih_b, E, nullptr, b4b, Xb, G4, BB, G4, E, 0);
    k_cell_plain<<<512, 256, 0, stream>>>(hbb, cbuf, Xb, 1);
    // forward LSTM: hoisted input gates (3 chunk GEMMs) + fused steps (proven R13 form)
    float* hp = hA;
    float* hq = hB;
    float* hlast = hA;
    for (int ch = 0; ch < 3; ++ch) {
        int t0 = ch * TCH;
        k_gemm_nt<64, 128, 4, 8><<<dim3(30, 32), 256, 0, stream>>>(
            emb + (size_t)t0 * BB * E, E, WihPk, E, nullptr, b4i, Xg, G4,
            TCH * BB, G4, E, 0);
        for (int s = 0; s < TCH; ++s) {
            int t = t0 + s;
            k_lstm_fused<<<512, 256, 0, stream>>>(
                hq, cbuf, Xg + (size_t)s * BG, WhhPk, hp, (t == 0) ? 1 : 0);
            hlast = hp;
            float* tmp = hp; hp = hq; hq = tmp;
        }
    }
    k_enc<<<128, 256, 0, stream>>>(hlast, hbb, out);

    // ================= image branch (reuses LSTM workspace) =================
    hipMemsetAsync(ssq, 0, NPX * 4, stream);
    k_pixssq<<<BB * 16, 256, 0, stream>>>(img, ssq);
    k_packB0<<<cdiv(16 * 9 * 1040 * 8, 256), 256, 0, stream>>>(conv0_w, wpk0);
    k_packBpm<<<cdiv(8 * 9 * 128 * 16, 256), 256, 0, stream>>>(r1c2_w, wpk1);
    k_packBpm<<<cdiv(8 * 9 * 128 * 16, 256), 256, 0, stream>>>(r2c2_w, wpk2);

    k_conv0<<<3136, 128, 0, stream>>>(img, ssq, wpk0, conv0_b, xa);
    hipMemsetAsync(stats, 0, 256 * 4, stream);
    k_bnstats<<<112, 256, 0, stream>>>(xa, xb, stats);
    k_apply_cat<<<cdiv(NPX * CM, 256), 256, 0, stream>>>(xa, xb, stats, bn0_g, bn0_b,
                                                         nullptr, vinr);

    // resblock 1 (1x1 conv as high-intensity GEMM)
    k_gemm_nt<128, 64, 8, 4><<<dim3(196, 2), 256, 0, stream>>>(
        vinr, CR, r1c1_w, CR, nullptr, r1c1_b, v1, CM, NPX, CM, CR, 1);
    k_conv_pm<<<1568, 128, 0, stream>>>(v1, wpk1, r1c2_b, xa);
    hipMemsetAsync(stats, 0, 256 * 4, stream);
    k_bnstats<<<112, 256, 0, stream>>>(xa, xb, stats);
    k_apply_cat<<<cdiv(NPX * CM, 256), 256, 0, stream>>>(xa, xb, stats, r1bn_g, r1bn_b,
                                                         v1, vinr);

    // resblock 2
    k_gemm_nt<128, 64, 8, 4><<<dim3(196, 2), 256, 0, stream>>>(
        vinr, CR, r2c1_w, CR, nullptr, r2c1_b, v1, CM, NPX, CM, CR, 1);
    k_conv_pm<<<1568, 128, 0, stream>>>(v1, wpk2, r2c2_b, xa);
    hipMemsetAsync(stats, 0, 256 * 4, stream);
    k_bnstats<<<112, 256, 0, stream>>>(xa, xb, stats);
    k_final<<<cdiv(NPX * CM, 256), 256, 0, stream>>>(xa, xb, stats, r2bn_g, r2bn_b,
                                                     v1, out + (size_t)BB * 2048);
}

// Round 16
// 3494.258 us; speedup vs baseline: 1.7382x; 1.0005x over previous
//
#include <hip/hip_runtime.h>
#include <math.h>

#define BB   128      // batch
#define T    45
#define E    300
#define HH   1024
#define G4   4096
#define HW   196      // 14*14
#define NPX  (BB*HW)  // 25088
#define C0   1026
#define CM   128
#define CR   130
#define TCH  15       // X-chunk timesteps (45 = 3*15)

static __device__ __forceinline__ float sigm(float x) { return 1.f / (1.f + __expf(-x)); }

// ---------------- embedding gather: emb[t][b][e] = lookup[que[b][t]][e] ----------------
__global__ void k_embed(const int* __restrict__ que, const float* __restrict__ lookup,
                        float* __restrict__ emb) {
    int idx = blockIdx.x * 256 + threadIdx.x;
    if (idx >= T * BB * E) return;
    int e = idx % E;
    int n = idx / E;
    int b = n % BB;
    int t = n / BB;
    int q = que[b * T + t];
    emb[idx] = lookup[(size_t)q * E + e];
}

// ---------------- generic NT GEMM: C[m][n] = sum A[m][k]*Bw[n][k] (+add)(+bias)(relu) ----
template <int BM, int BN, int TM, int TN>
__global__ __launch_bounds__(256) void k_gemm_nt(
    const float* __restrict__ A, int lda,
    const float* __restrict__ Bw, int ldb,
    const float* __restrict__ add,
    const float* __restrict__ bias,
    float* __restrict__ C, int ldc,
    int M, int N, int K, int relu) {
    constexpr int KT = 16;
    constexpr int TX = BN / TN;
    __shared__ alignas(16) float As[KT][BM + 4];
    __shared__ alignas(16) float Bs[KT][BN + 4];
    const int tid = threadIdx.x;
    const int tx = tid % TX, ty = tid / TX;
    const int r0 = blockIdx.x * BM, c0 = blockIdx.y * BN;
    float acc[TM][TN] = {};
    for (int k0 = 0; k0 < K; k0 += KT) {
#pragma unroll
        for (int l = tid; l < BM * KT; l += 256) {
            int m = l / KT, k = l % KT;
            int gm = r0 + m, gk = k0 + k;
            As[k][m] = (gm < M && gk < K) ? A[(size_t)gm * lda + gk] : 0.f;
        }
#pragma unroll
        for (int l = tid; l < BN * KT; l += 256) {
            int n = l / KT, k = l % KT;
            int gn = c0 + n, gk = k0 + k;
            Bs[k][n] = (gn < N && gk < K) ? Bw[(size_t)gn * ldb + gk] : 0.f;
        }
        __syncthreads();
#pragma unroll
        for (int k = 0; k < KT; ++k) {
            float ar[TM], br[TN];
            if constexpr ((TM & 3) == 0) {
#pragma unroll
                for (int i = 0; i < TM; i += 4) {
                    float4 v = *(const float4*)&As[k][ty * TM + i];
                    ar[i] = v.x; ar[i + 1] = v.y; ar[i + 2] = v.z; ar[i + 3] = v.w;
                }
            } else if constexpr ((TM & 1) == 0) {
#pragma unroll
                for (int i = 0; i < TM; i += 2) {
                    float2 v = *(const float2*)&As[k][ty * TM + i];
                    ar[i] = v.x; ar[i + 1] = v.y;
                }
            } else {
#pragma unroll
                for (int i = 0; i < TM; ++i) ar[i] = As[k][ty * TM + i];
            }
            if constexpr ((TN & 3) == 0) {
#pragma unroll
                for (int j = 0; j < TN; j += 4) {
                    float4 v = *(const float4*)&Bs[k][tx * TN + j];
                    br[j] = v.x; br[j + 1] = v.y; br[j + 2] = v.z; br[j + 3] = v.w;
                }
            } else if constexpr ((TN & 1) == 0) {
#pragma unroll
                for (int j = 0; j < TN; j += 2) {
                    float2 v = *(const float2*)&Bs[k][tx * TN + j];
                    br[j] = v.x; br[j + 1] = v.y;
                }
            } else {
#pragma unroll
                for (int j = 0; j < TN; ++j) br[j] = Bs[k][tx * TN + j];
            }
#pragma unroll
            for (int i = 0; i < TM; ++i)
#pragma unroll
                for (int j = 0; j < TN; ++j) acc[i][j] += ar[i] * br[j];
        }
        __syncthreads();
    }
#pragma unroll
    for (int i = 0; i < TM; ++i) {
        int gm = r0 + ty * TM + i;
        if (gm >= M) continue;
#pragma unroll
        for (int j = 0; j < TN; ++j) {
            int gn = c0 + tx * TN + j;
            if (gn >= N) continue;
            float v = acc[i][j];
            if (add) v += add[(size_t)gm * ldc + gn];
            if (bias) v += bias[gn];
            if (relu) v = fmaxf(v, 0.f);
            C[(size_t)gm * ldc + gn] = v;
        }
    }
}

// ---------------- LSTM packs (merged): gate-interleaved n = 4*unit + gate ----------------
__global__ void k_pack_w(const float* __restrict__ Wih, const float* __restrict__ Whh,
                         float* __restrict__ oih, float* __restrict__ ohh) {
    int idx = blockIdx.x * 256 + threadIdx.x;
    const int NIH = G4 * E;
    if (idx < NIH) {
        int k = idx % E;
        int n = idx / E;
        oih[idx] = Wih[(size_t)((n & 3) * HH + (n >> 2)) * E + k];
    } else {
        int j = idx - NIH;
        if (j < G4 * HH) {
            int k = j & 1023;
            int n = j >> 10;
            ohh[j] = Whh[(size_t)((n & 3) * HH + (n >> 2)) * HH + k];
        }
    }
}
__global__ void k_pack_bias(const float* __restrict__ bih_f, const float* __restrict__ bhh_f,
                            const float* __restrict__ bih_b, const float* __restrict__ bhh_b,
                            float* __restrict__ b4i, float* __restrict__ b4b) {
    int idx = blockIdx.x * 256 + threadIdx.x;
    if (idx < G4) {
        int r = (idx & 3) * HH + (idx >> 2);
        b4i[idx] = bih_f[r] + bhh_f[r];
    } else if (idx < 2 * G4) {
        int n = idx - G4;
        b4b[n] = bih_b[n] + bhh_b[n];
    }
}

// ---------------- plain cell (backward LSTM, natural gate layout i,f,g,o) ----------------
__global__ void k_cell_plain(float* __restrict__ h, float* __restrict__ c,
                             const float* __restrict__ gx, int first) {
    int idx = blockIdx.x * 256 + threadIdx.x;   // < BB*HH
    int b = idx >> 10, j = idx & 1023;
    size_t base = (size_t)b * G4 + j;
    float gi = gx[base], gf = gx[base + HH], gg = gx[base + 2 * HH], go = gx[base + 3 * HH];
    float cp = first ? 0.f : c[idx];
    float cn = sigm(gf) * cp + sigm(gi) * tanhf(gg);
    c[idx] = cn;
    h[idx] = sigm(go) * tanhf(cn);
}

// ---------------- fused LSTM recurrent step: acc = h @ WhhPk^T; gates = acc + gx --------
// 512 blocks (16 rows x 64 cols each) = 2 blocks/CU; XCD-clustered. 2-deep prefetch.
// gx/c loads hoisted before the K-loop so their latency hides under compute.
__global__ __launch_bounds__(256) void k_lstm_fused(
    const float* __restrict__ h_in, float* __restrict__ c_io,
    const float* __restrict__ gx,
    const float* __restrict__ Wpk,
    float* __restrict__ h_out, int first) {
    __shared__ alignas(16) float As[16][20];
    __shared__ alignas(16) float Bs[16][68];
    const int tid = threadIdx.x;
    const int tx = tid & 15, ty = tid >> 4;
    const int id = blockIdx.x;
    const int xcd = id & 7, slot = id >> 3;       // 64 slots per XCD
    const int cg = xcd * 8 + (slot >> 3);         // column-group 0..63 (64 cols each)
    const int rb = slot & 7;                      // row-block 0..7 (16 rows each)
    const int r0 = rb * 16;
    const int c0 = cg * 64;
    const int ka = tid & 15, ma = tid >> 4;
    const int b = r0 + ty;
    const int jj4 = c0 + tx * 4;    // 4 consecutive packed cols = one unit's i,f,g,o
    const int u = jj4 >> 2;
    const size_t ci = (size_t)b * HH + u;
    // hoisted epilogue loads (latency hidden under K-loop)
    float4 g4 = *(const float4*)&gx[(size_t)b * G4 + jj4];
    float cp = first ? 0.f : c_io[ci];
    float acc[4] = {};

    if (!first) {
        const float* hrow = h_in + (size_t)(r0 + ma) * HH + ka;
        const float* wp0 = Wpk + (size_t)(c0 + ma) * HH + ka;
        float aA = hrow[0];
        float b0A = wp0[0], b1A = wp0[16 * HH], b2A = wp0[32 * HH], b3A = wp0[48 * HH];
        float aB = hrow[16];
        float b0B = wp0[16], b1B = wp0[16 * HH + 16], b2B = wp0[32 * HH + 16],
              b3B = wp0[48 * HH + 16];
        for (int k0 = 0; k0 < HH; k0 += 16) {
            As[ka][ma] = aA;
            Bs[ka][ma] = b0A;
            Bs[ka][ma + 16] = b1A;
            Bs[ka][ma + 32] = b2A;
            Bs[ka][ma + 48] = b3A;
            __syncthreads();
            aA = aB; b0A = b0B; b1A = b1B; b2A = b2B; b3A = b3B;
            if (k0 + 32 < HH) {
                int o = k0 + 32;
                aB = hrow[o];
                b0B = wp0[o];
                b1B = wp0[16 * HH + o];
                b2B = wp0[32 * HH + o];
                b3B = wp0[48 * HH + o];
            }
#pragma unroll
            for (int k = 0; k < 16; ++k) {
                float a = As[k][ty];
                float4 b4 = *(const float4*)&Bs[k][tx * 4];
                acc[0] += a * b4.x;
                acc[1] += a * b4.y;
                acc[2] += a * b4.z;
                acc[3] += a * b4.w;
            }
            __syncthreads();
        }
    }
    float gi = acc[0] + g4.x;
    float gf = acc[1] + g4.y;
    float gg = acc[2] + g4.z;
    float go = acc[3] + g4.w;
    float cn = sigm(gf) * cp + sigm(gi) * tanhf(gg);
    c_io[ci] = cn;
    h_out[ci] = sigm(go) * tanhf(cn);
}

// ---------------- enc: l2norm(concat(hf, hb)) per batch row ----------------
__global__ void k_enc(const float* __restrict__ hf, const float* __restrict__ hb,
                      float* __restrict__ out) {
    int b = blockIdx.x;
    int tid = threadIdx.x;
    float vals[8];
    float ss = 0.f;
#pragma unroll
    for (int i = 0; i < 8; ++i) {
        int j = i * 256 + tid;
        float v = (j < HH) ? hf[(size_t)b * HH + j] : hb[(size_t)b * HH + (j - HH)];
        vals[i] = v;
        ss += v * v;
    }
    __shared__ float red[256];
    red[tid] = ss;
    __syncthreads();
    for (int s = 128; s > 0; s >>= 1) {
        if (tid < s) red[tid] += red[tid + s];
        __syncthreads();
    }
    float scale = 1.f / fmaxf(sqrtf(red[0]), 1e-12f);
#pragma unroll
    for (int i = 0; i < 8; ++i) out[(size_t)b * 2048 + i * 256 + tid] = vals[i] * scale;
}

// ---------------- per-pixel sum of squares over 1024 channels ----------------
__global__ void k_pixssq(const float* __restrict__ img, float* __restrict__ ssq) {
    int b = blockIdx.x >> 4;
    int cc = (blockIdx.x & 15) * 64;
    int p = threadIdx.x;
    if (p >= HW) return;
    const float* base = img + ((size_t)b * 1024 + cc) * HW + p;
    float acc = 0.f;
#pragma unroll 4
    for (int c = 0; c < 64; ++c) {
        float v = base[(size_t)c * HW];
        acc += v * v;
    }
    atomicAdd(&ssq[b * HW + p], acc);
}

// ---------------- weight packs: conv0 [ocg16][tap][k][8 oc]; conv_pm [ocg8][tap][k][16 oc] ----
__global__ void k_packB0(const float* __restrict__ w, float* __restrict__ o) {
    int idx = blockIdx.x * 256 + threadIdx.x;
    if (idx >= 16 * 9 * 1040 * 8) return;
    int oi = idx & 7;
    int r = idx >> 3;
    int c = r % 1040;
    int gt = r / 1040;
    int tap = gt % 9, ocg = gt / 9;
    o[idx] = (c < C0) ? w[((size_t)(ocg * 8 + oi) * C0 + c) * 9 + tap] : 0.f;
}
__global__ void k_packBpm(const float* __restrict__ w, float* __restrict__ o) {
    int idx = blockIdx.x * 256 + threadIdx.x;
    if (idx >= 8 * 9 * 128 * 16) return;
    int oi = idx & 15;
    int r = idx >> 4;
    int c = r % 128;
    int gt = r / 128;
    int tap = gt % 9, ocg = gt / 9;
    o[idx] = w[((size_t)(ocg * 16 + oi) * 128 + c) * 9 + tap];
}

// XCD-clustered swizzles
static __device__ __forceinline__ void conv_swz3136(int id, int& g, int& ocg, int& z) {
    int s2 = (id & 7) * 392 + (id >> 3);
    g = s2 >> 5;
    int cb = s2 & 31;
    ocg = cb >> 1;
    z = cb & 1;
}
static __device__ __forceinline__ void conv_swz1568(int id, int& g, int& ocg, int& z) {
    int s2 = (id & 7) * 196 + (id >> 3);
    g = s2 >> 4;
    int cb = s2 & 15;
    ocg = cb >> 1;
    z = cb & 1;
}

// ---------------- conv0: [k][pixel] LDS, K-step 8, 256-px tile, ocg=16 split ----------
// Also zeroes stats[256] (block 0) so the follow-up bnstats needs no memset.
__global__ __launch_bounds__(128) void k_conv0(const float* __restrict__ img,
                                               const float* __restrict__ ssq,
                                               const float* __restrict__ wpk,
                                               const float* __restrict__ bias,
                                               float* __restrict__ outParts,
                                               float* __restrict__ stats) {
    __shared__ float As[8][292];   // [k][slot]; slot 288 forced zero
    const int tid = threadIdx.x;
    if (blockIdx.x == 0 && tid < 128) {
        stats[tid] = 0.f;
        stats[128 + tid] = 0.f;
    }
    int g, ocg, z;
    conv_swz3136(blockIdx.x, g, ocg, z);
    const int kbeg = z ? 528 : 0;
    const int kend = z ? 1032 : 528;   // weights >=1026 are zero -> stop at 1032
    float* out = outParts + (size_t)z * NPX * CM;
    const int P0 = g * 256;
    const int gp1 = P0 + tid;
    const int gp2 = gp1 + 128;
    const int p1 = gp1 % HW, p2 = gp2 % HW;
    const int y1 = p1 / 14, x1 = p1 % 14;
    const int y2 = p2 / 14, x2 = p2 % 14;

    const float* sptr[3];
    float sinv[3], scy[3], scx[3];
#pragma unroll
    for (int j = 0; j < 3; ++j) {
        int s = tid + j * 128;
        int gp = P0 - 16 + s;
        bool ok = (s < 288) && (gp >= 0) && (gp < NPX);
        int gpc = ok ? gp : 0;
        int pp = gpc % HW;
        int bi = gpc / HW;
        sptr[j] = img + ((size_t)bi * 1024) * HW + pp;
        sinv[j] = ok ? (1.f / fmaxf(sqrtf(ssq[gpc]), 1e-12f)) : 0.f;
        scy[j] = ok ? (float)(pp / 14 - 7) * (1.f / 7.f) : 0.f;
        scx[j] = ok ? (float)(pp % 14 - 7) * (1.f / 7.f) : 0.f;
    }

    float acc0[8] = {};
    float acc1[8] = {};
    for (int k0 = kbeg; k0 < kend; k0 += 8) {
        __syncthreads();
        if (k0 != 1024) {
#pragma unroll
            for (int j = 0; j < 3; ++j) {
                int s = tid + j * 128;
                if (j < 2 || s < 292) {
                    const float* pb = sptr[j] + (size_t)k0 * HW;
                    float inv = sinv[j];
#pragma unroll
                    for (int k = 0; k < 8; ++k) As[k][s] = pb[(size_t)k * HW] * inv;
                }
            }
        } else {
#pragma unroll
            for (int j = 0; j < 3; ++j) {
                int s = tid + j * 128;
                if (j < 2 || s < 292) {
                    As[0][s] = scy[j];
                    As[1][s] = scx[j];
#pragma unroll
                    for (int k = 2; k < 8; ++k) As[k][s] = 0.f;
                }
            }
        }
        __syncthreads();
        for (int tap = 0; tap < 9; ++tap) {
            const int ky = tap / 3 - 1, kx = tap % 3 - 1;
            const int d = ky * 14 + kx;
            const int of1 = ((unsigned)(y1 + ky) < 14u && (unsigned)(x1 + kx) < 14u)
                                ? (tid + 16 + d) : 288;
            const int of2 = ((unsigned)(y2 + ky) < 14u && (unsigned)(x2 + kx) < 14u)
                                ? (tid + 144 + d) : 288;
            const float4* __restrict__ wq =
                (const float4*)wpk + ((size_t)(ocg * 9 + tap) * 1040 + k0) * 2;
#pragma unroll
            for (int k = 0; k < 8; ++k) {
                float a = As[k][of1];
                float b = As[k][of2];
                float4 w0 = wq[0], w1 = wq[1];
                wq += 2;
                acc0[0] += a * w0.x;  acc1[0] += b * w0.x;
                acc0[1] += a * w0.y;  acc1[1] += b * w0.y;
                acc0[2] += a * w0.z;  acc1[2] += b * w0.z;
                acc0[3] += a * w0.w;  acc1[3] += b * w0.w;
                acc0[4] += a * w1.x;  acc1[4] += b * w1.x;
                acc0[5] += a * w1.y;  acc1[5] += b * w1.y;
                acc0[6] += a * w1.z;  acc1[6] += b * w1.z;
                acc0[7] += a * w1.w;  acc1[7] += b * w1.w;
            }
        }
    }
    const float* bp = bias + ocg * 8;
    float* op1 = out + (size_t)gp1 * CM + ocg * 8;
    float* op2 = out + (size_t)gp2 * CM + ocg * 8;
#pragma unroll
    for (int qq = 0; qq < 2; ++qq) {
        float b0 = z ? 0.f : bp[qq * 4 + 0];
        float b1 = z ? 0.f : bp[qq * 4 + 1];
        float b2 = z ? 0.f : bp[qq * 4 + 2];
        float b3 = z ? 0.f : bp[qq * 4 + 3];
        float4 r0, r1;
        r0.x = acc0[qq * 4 + 0] + b0;  r1.x = acc1[qq * 4 + 0] + b0;
        r0.y = acc0[qq * 4 + 1] + b1;  r1.y = acc1[qq * 4 + 1] + b1;
        r0.z = acc0[qq * 4 + 2] + b2;  r1.z = acc1[qq * 4 + 2] + b2;
        r0.w = acc0[qq * 4 + 3] + b3;  r1.w = acc1[qq * 4 + 3] + b3;
        *(float4*)&op1[qq * 4] = r0;
        *(float4*)&op2[qq * 4] = r1;
    }
}

// ---------------- 3x3 pad1 conv, pixel-major [NPX][128], ocg=8 (16 oc), K-step 8 --------
// Also zeroes stats[256] (block 0).
__global__ __launch_bounds__(128) void k_conv_pm(const float* __restrict__ vin,
                                                 const float* __restrict__ wpk,
                                                 const float* __restrict__ bias,
                                                 float* __restrict__ outParts,
                                                 float* __restrict__ stats) {
    __shared__ float As[8][292];
    const int tid = threadIdx.x;
    if (blockIdx.x == 0 && tid < 128) {
        stats[tid] = 0.f;
        stats[128 + tid] = 0.f;
    }
    int g, ocg, z;
    conv_swz1568(blockIdx.x, g, ocg, z);
    const int kbeg = z * 64;
    float* out = outParts + (size_t)z * NPX * CM;
    const int P0 = g * 256;
    const int gp1 = P0 + tid;
    const int gp2 = gp1 + 128;
    const int p1 = gp1 % HW, p2 = gp2 % HW;
    const int y1 = p1 / 14, x1 = p1 % 14;
    const int y2 = p2 / 14, x2 = p2 % 14;

    const float* sptr[3];
    float smask[3];
#pragma unroll
    for (int j = 0; j < 3; ++j) {
        int s = tid + j * 128;
        int gp = P0 - 16 + s;
        bool ok = (s < 288) && (gp >= 0) && (gp < NPX);
        sptr[j] = vin + (size_t)(ok ? gp : 0) * CM;
        smask[j] = ok ? 1.f : 0.f;
    }

    float acc0[16] = {};
    float acc1[16] = {};
    for (int k0 = kbeg; k0 < kbeg + 64; k0 += 8) {
        __syncthreads();
#pragma unroll
        for (int j = 0; j < 3; ++j) {
            int s = tid + j * 128;
            if (j < 2 || s < 292) {
                float4 v0 = *(const float4*)&sptr[j][k0];
                float4 v1 = *(const float4*)&sptr[j][k0 + 4];
                float m = smask[j];
                As[0][s] = v0.x * m;
                As[1][s] = v0.y * m;
                As[2][s] = v0.z * m;
                As[3][s] = v0.w * m;
                As[4][s] = v1.x * m;
                As[5][s] = v1.y * m;
                As[6][s] = v1.z * m;
                As[7][s] = v1.w * m;
            }
        }
        __syncthreads();
        for (int tap = 0; tap < 9; ++tap) {
            const int ky = tap / 3 - 1, kx = tap % 3 - 1;
            const int d = ky * 14 + kx;
            const int of1 = ((unsigned)(y1 + ky) < 14u && (unsigned)(x1 + kx) < 14u)
                                ? (tid + 16 + d) : 288;
            const int of2 = ((unsigned)(y2 + ky) < 14u && (unsigned)(x2 + kx) < 14u)
                                ? (tid + 144 + d) : 288;
            const float4* __restrict__ wq =
                (const float4*)wpk + ((size_t)(ocg * 9 + tap) * 128 + k0) * 4;
#pragma unroll
            for (int k = 0; k < 8; ++k) {
                float a = As[k][of1];
                float b = As[k][of2];
                float4 w0 = wq[0], w1 = wq[1], w2 = wq[2], w3 = wq[3];
                wq += 4;
                acc0[0]  += a * w0.x;  acc1[0]  += b * w0.x;
                acc0[1]  += a * w0.y;  acc1[1]  += b * w0.y;
                acc0[2]  += a * w0.z;  acc1[2]  += b * w0.z;
                acc0[3]  += a * w0.w;  acc1[3]  += b * w0.w;
                acc0[4]  += a * w1.x;  acc1[4]  += b * w1.x;
                acc0[5]  += a * w1.y;  acc1[5]  += b * w1.y;
                acc0[6]  += a * w1.z;  acc1[6]  += b * w1.z;
                acc0[7]  += a * w1.w;  acc1[7]  += b * w1.w;
                acc0[8]  += a * w2.x;  acc1[8]  += b * w2.x;
                acc0[9]  += a * w2.y;  acc1[9]  += b * w2.y;
                acc0[10] += a * w2.z;  acc1[10] += b * w2.z;
                acc0[11] += a * w2.w;  acc1[11] += b * w2.w;
                acc0[12] += a * w3.x;  acc1[12] += b * w3.x;
                acc0[13] += a * w3.y;  acc1[13] += b * w3.y;
                acc0[14] += a * w3.z;  acc1[14] += b * w3.z;
                acc0[15] += a * w3.w;  acc1[15] += b * w3.w;
            }
        }
    }
    const float* bp = bias + ocg * 16;
    float* op1 = out + (size_t)gp1 * CM + ocg * 16;
    float* op2 = out + (size_t)gp2 * CM + ocg * 16;
#pragma unroll
    for (int qq = 0; qq < 4; ++qq) {
        float b0 = z ? 0.f : bp[qq * 4 + 0];
        float b1 = z ? 0.f : bp[qq * 4 + 1];
        float b2 = z ? 0.f : bp[qq * 4 + 2];
        float b3 = z ? 0.f : bp[qq * 4 + 3];
        float4 r0, r1;
        r0.x = acc0[qq * 4 + 0] + b0;  r1.x = acc1[qq * 4 + 0] + b0;
        r0.y = acc0[qq * 4 + 1] + b1;  r1.y = acc1[qq * 4 + 1] + b1;
        r0.z = acc0[qq * 4 + 2] + b2;  r1.z = acc1[qq * 4 + 2] + b2;
        r0.w = acc0[qq * 4 + 3] + b3;  r1.w = acc1[qq * 4 + 3] + b3;
        *(float4*)&op1[qq * 4] = r0;
        *(float4*)&op2[qq * 4] = r1;
    }
}

// ---------------- BN train stats over 2 parts (stats pre-zeroed by conv kernel) ----------
__global__ void k_bnstats(const float* __restrict__ xa, const float* __restrict__ xb,
                          float* __restrict__ stats) {
    int r0 = blockIdx.x * 224;
    int c = threadIdx.x & 127, rh = threadIdx.x >> 7;
    float s = 0.f, ss = 0.f;
    for (int r = r0 + rh; r < r0 + 224; r += 2) {
        float v = xa[(size_t)r * CM + c] + xb[(size_t)r * CM + c];
        s += v;
        ss += v * v;
    }
    __shared__ float rs[256], rss[256];
    rs[threadIdx.x] = s;
    rss[threadIdx.x] = ss;
    __syncthreads();
    if (threadIdx.x < 128) {
        s = rs[threadIdx.x] + rs[threadIdx.x + 128];
        ss = rss[threadIdx.x] + rss[threadIdx.x + 128];
        atomicAdd(&stats[c], s);
        atomicAdd(&stats[128 + c], ss);
    }
}

// ---------------- relu(bn(xa+xb)) (+addv) -> vinr[p][c] (stride 130), BN-final inline ----
__global__ void k_apply_cat(const float* __restrict__ xa, const float* __restrict__ xb,
                            const float* __restrict__ stats,
                            const float* __restrict__ gg, const float* __restrict__ bb,
                            const float* __restrict__ addv, float* __restrict__ vinr) {
    int idx = blockIdx.x * 256 + threadIdx.x;
    if (idx >= NPX * CM) return;
    int c = idx & 127;
    int p = idx >> 7;
    float mean = stats[c] * (1.f / (float)NPX);
    float var = stats[128 + c] * (1.f / (float)NPX) - mean * mean;
    float sc = gg[c] * rsqrtf(var + 1e-5f);
    float sh = bb[c] - mean * sc;
    float v = fmaxf((xa[idx] + xb[idx]) * sc + sh, 0.f);
    if (addv) v += addv[idx];
    vinr[(size_t)p * CR + c] = v;
    if (c < 2) {
        int pp = p % HW;
        float cv = (c == 0) ? (float)(pp / 14 - 7) * (1.f / 7.f)
                            : (float)(pp % 14 - 7) * (1.f / 7.f);
        vinr[(size_t)p * CR + 128 + c] = cv;
    }
}

// ---------------- final: relu(bn(xa+xb)) + v1, transpose to NCHW, BN-final inline ----------
__global__ void k_final(const float* __restrict__ xa, const float* __restrict__ xb,
                        const float* __restrict__ stats,
                        const float* __restrict__ gg, const float* __restrict__ bb,
                        const float* __restrict__ addv, float* __restrict__ outv) {
    int idx = blockIdx.x * 256 + threadIdx.x;
    if (idx >= NPX * CM) return;
    int p = idx % HW;
    int o = (idx / HW) & 127;
    int b = idx / (HW * CM);
    float mean = stats[o] * (1.f / (float)NPX);
    float var = stats[128 + o] * (1.f / (float)NPX) - mean * mean;
    float sc = gg[o] * rsqrtf(var + 1e-5f);
    float sh = bb[o] - mean * sc;
    size_t pm = ((size_t)b * HW + p) * CM + o;
    outv[idx] = fmaxf((xa[pm] + xb[pm]) * sc + sh, 0.f) + addv[pm];
}

extern "C" void kernel_launch(void* const* d_in, const int* in_sizes, int n_in,
                              void* d_out, int out_size, void* d_ws, size_t ws_size,
                              hipStream_t stream) {
    const int* que = (const int*)d_in[0];
    const float* img = (const float*)d_in[1];
    const float* lookup = (const float*)d_in[2];
    const float* Wih_f = (const float*)d_in[3];
    const float* Whh_f = (const float*)d_in[4];
    const float* bih_f = (const float*)d_in[5];
    const float* bhh_f = (const float*)d_in[6];
    const float* Wih_b = (const float*)d_in[7];
    const float* bih_b = (const float*)d_in[9];
    const float* bhh_b = (const float*)d_in[10];
    const float* conv0_w = (const float*)d_in[11];
    const float* conv0_b = (const float*)d_in[12];
    const float* bn0_g = (const float*)d_in[13];
    const float* bn0_b = (const float*)d_in[14];
    const float* r1c1_w = (const float*)d_in[15];
    const float* r1c1_b = (const float*)d_in[16];
    const float* r1c2_w = (const float*)d_in[17];
    const float* r1c2_b = (const float*)d_in[18];
    const float* r1bn_g = (const float*)d_in[19];
    const float* r1bn_b = (const float*)d_in[20];
    const float* r2c1_w = (const float*)d_in[21];
    const float* r2c1_b = (const float*)d_in[22];
    const float* r2c2_w = (const float*)d_in[23];
    const float* r2c2_b = (const float*)d_in[24];
    const float* r2bn_g = (const float*)d_in[25];
    const float* r2bn_b = (const float*)d_in[26];
    float* out = (float*)d_out;

    float* ws = (float*)d_ws;
    // ---- LSTM region (dead after k_enc; image region overlays) ----
    float* emb = ws;                         // 1,728,000
    float* Xg = emb + 1728000;               // 7,864,320  (15 x 128 x 4096)
    float* WihPk = Xg + 7864320;             // 1,228,800  (4096 x 300)
    float* WhhPk = WihPk + 1228800;          // 4,194,304  (4096 x 1024)
    float* b4i = WhhPk + 4194304;            // 4,096
    float* b4b = b4i + 4096;                 // 4,096
    float* Xb = b4b + 4096;                  // 524,288
    float* hA = Xb + 524288;                 // 131,072
    float* hB = hA + 131072;                 // 131,072
    float* cbuf = hB + 131072;               // 131,072
    float* hbb = cbuf + 131072;              // 131,072
    size_t lstm_end = (size_t)(hbb + 131072 - ws);
    // ---- image region (overlays LSTM region) ----
    float* ssq = ws;                         // 25,088
    float* wpk0 = ssq + 25088;               // 1,198,080
    float* wpk1 = wpk0 + 1198080;            // 147,456
    float* wpk2 = wpk1 + 147456;             // 147,456
    float* xa = wpk2 + 147456;               // 3,211,264  (part 0)
    float* xb = xa + 3211264;                // 3,211,264  (part 1)
    float* vinr = xb + 3211264;              // 3,261,440
    float* v1 = vinr + 3261440;              // 3,211,264
    float* stats = v1 + 3211264;             // 256
    size_t img_end = (size_t)(stats + 256 - ws);
    size_t need = (lstm_end > img_end ? lstm_end : img_end) * 4;
    if (ws_size < need) return;

    auto cdiv = [](int a, int b) { return (a + b - 1) / b; };
    const size_t BG = (size_t)BB * G4;

    // ================= LSTM branch =================
    k_embed<<<cdiv(T * BB * E, 256), 256, 0, stream>>>(que, lookup, emb);
    k_pack_w<<<cdiv(G4 * E + G4 * HH, 256), 256, 0, stream>>>(Wih_f, Whh_f, WihPk, WhhPk);
    k_pack_bias<<<32, 256, 0, stream>>>(bih_f, bhh_f, bih_b, bhh_b, b4i, b4b);
    // backward LSTM: only position T-1 used (natural layout)
    k_gemm_nt<64, 64, 4, 4><<<dim3(2, 64), 256, 0, stream>>>(
        emb + (size_t)(T - 1) * BB * E, E, Wih_b, E, nullptr, b4b, Xb, G4, BB, G4, E, 0);
    k_cell_plain<<<512, 256, 0, stream>>>(hbb, cbuf, Xb, 1);
    // forward LSTM: hoisted input gates (3 chunk GEMMs) + fused steps (proven R13 form)
    float* hp = hA;
    float* hq = hB;
    float* hlast = hA;
    for (int ch = 0; ch < 3; ++ch) {
        int t0 = ch * TCH;
        k_gemm_nt<64, 128, 4, 8><<<dim3(30, 32), 256, 0, stream>>>(
            emb + (size_t)t0 * BB * E, E, WihPk, E, nullptr, b4i, Xg, G4,
            TCH * BB, G4, E, 0);
        for (int s = 0; s < TCH; ++s) {
            int t = t0 + s;
            k_lstm_fused<<<512, 256, 0, stream>>>(
                hq, cbuf, Xg + (size_t)s * BG, WhhPk, hp, (t == 0) ? 1 : 0);
            hlast = hp;
            float* tmp = hp; hp = hq; hq = tmp;
        }
    }
    k_enc<<<128, 256, 0, stream>>>(hlast, hbb, out);

    // ================= image branch (reuses LSTM workspace) =================
    hipMemsetAsync(ssq, 0, NPX * 4, stream);
    k_pixssq<<<BB * 16, 256, 0, stream>>>(img, ssq);
    k_packB0<<<cdiv(16 * 9 * 1040 * 8, 256), 256, 0, stream>>>(conv0_w, wpk0);
    k_packBpm<<<cdiv(8 * 9 * 128 * 16, 256), 256, 0, stream>>>(r1c2_w, wpk1);
    k_packBpm<<<cdiv(8 * 9 * 128 * 16, 256), 256, 0, stream>>>(r2c2_w, wpk2);

    k_conv0<<<3136, 128, 0, stream>>>(img, ssq, wpk0, conv0_b, xa, stats);
    k_bnstats<<<112, 256, 0, stream>>>(xa, xb, stats);
    k_apply_cat<<<cdiv(NPX * CM, 256), 256, 0, stream>>>(xa, xb, stats, bn0_g, bn0_b,
                                                         nullptr, vinr);

    // resblock 1 (1x1 conv as high-intensity GEMM)
    k_gemm_nt<128, 64, 8, 4><<<dim3(196, 2), 256, 0, stream>>>(
        vinr, CR, r1c1_w, CR, nullptr, r1c1_b, v1, CM, NPX, CM, CR, 1);
    k_conv_pm<<<1568, 128, 0, stream>>>(v1, wpk1, r1c2_b, xa, stats);
    k_bnstats<<<112, 256, 0, stream>>>(xa, xb, stats);
    k_apply_cat<<<cdiv(NPX * CM, 256), 256, 0, stream>>>(xa, xb, stats, r1bn_g, r1bn_b,
                                                         v1, vinr);

    // resblock 2
    k_gemm_nt<128, 64, 8, 4><<<dim3(196, 2), 256, 0, stream>>>(
        vinr, CR, r2c1_w, CR, nullptr, r2c1_b, v1, CM, NPX, CM, CR, 1);
    k_conv_pm<<<1568, 128, 0, stream>>>(v1, wpk2, r2c2_b, xa, stats);
    k_bnstats<<<112, 256, 0, stream>>>(xa, xb, stats);
    k_final<<<cdiv(NPX * CM, 256), 256, 0, stream>>>(xa, xb, stats, r2bn_g, r2bn_b,
                                                     v1, out + (size_t)BB * 2048);
}